// Round 1
// baseline (1012.623 us; speedup 1.0000x reference)
//
#include <hip/hip_runtime.h>
#include <cstdint>
#include <cstddef>

static constexpr int kT  = 2048;
static constexpr int kD  = 512;
static constexpr int kB  = 2;
static constexpr int kN  = kB * kT;   // 4096 rows
static constexpr float kNegInf = -1e30f;

// ---------------------------------------------------------------- GEMM
// C[M,Nn] = A[M,K] @ W[Nn,K]^T + bias, optional relu.
// BM=128, BN=64, BK=16, 256 threads, 8x4 micro-tile per thread.
__global__ __launch_bounds__(256, 2) void gemm_kernel(
    const float* __restrict__ A, const float* __restrict__ W,
    const float* __restrict__ bias, float* __restrict__ C,
    int M, int Nn, int K, int relu)
{
  constexpr int BM = 128, BN = 64, BK = 16;
  __shared__ float As[BK][BM + 4];   // transposed: As[k][m]
  __shared__ float Bs[BK][BN + 4];   // transposed: Bs[k][n]
  const int tid = threadIdx.x;
  const int tx = tid & 15, ty = tid >> 4;
  const int m0 = blockIdx.x * BM, n0 = blockIdx.y * BN;

  float acc[8][4];
#pragma unroll
  for (int i = 0; i < 8; ++i)
#pragma unroll
    for (int j = 0; j < 4; ++j) acc[i][j] = 0.f;

  for (int k0 = 0; k0 < K; k0 += BK) {
#pragma unroll
    for (int i = 0; i < 2; ++i) {
      int f = tid + 256 * i;            // 512 float4 = 128x16
      int row = f >> 2, c4 = (f & 3) * 4;
      float4 v = *reinterpret_cast<const float4*>(&A[(size_t)(m0 + row) * K + k0 + c4]);
      As[c4 + 0][row] = v.x; As[c4 + 1][row] = v.y;
      As[c4 + 2][row] = v.z; As[c4 + 3][row] = v.w;
    }
    {
      int row = tid >> 2, c4 = (tid & 3) * 4;  // 256 float4 = 64x16
      float4 v = *reinterpret_cast<const float4*>(&W[(size_t)(n0 + row) * K + k0 + c4]);
      Bs[c4 + 0][row] = v.x; Bs[c4 + 1][row] = v.y;
      Bs[c4 + 2][row] = v.z; Bs[c4 + 3][row] = v.w;
    }
    __syncthreads();
#pragma unroll
    for (int kk = 0; kk < BK; ++kk) {
      float4 a0 = *reinterpret_cast<const float4*>(&As[kk][ty * 8]);
      float4 a1 = *reinterpret_cast<const float4*>(&As[kk][ty * 8 + 4]);
      float4 b0 = *reinterpret_cast<const float4*>(&Bs[kk][tx * 4]);
      float a[8] = {a0.x, a0.y, a0.z, a0.w, a1.x, a1.y, a1.z, a1.w};
      float b[4] = {b0.x, b0.y, b0.z, b0.w};
#pragma unroll
      for (int i = 0; i < 8; ++i)
#pragma unroll
        for (int j = 0; j < 4; ++j)
          acc[i][j] = fmaf(a[i], b[j], acc[i][j]);
    }
    __syncthreads();
  }

  float bv[4] = {0.f, 0.f, 0.f, 0.f};
  if (bias) {
#pragma unroll
    for (int j = 0; j < 4; ++j) bv[j] = bias[n0 + tx * 4 + j];
  }
#pragma unroll
  for (int i = 0; i < 8; ++i) {
    float4 o;
    o.x = acc[i][0] + bv[0]; o.y = acc[i][1] + bv[1];
    o.z = acc[i][2] + bv[2]; o.w = acc[i][3] + bv[3];
    if (relu) {
      o.x = fmaxf(o.x, 0.f); o.y = fmaxf(o.y, 0.f);
      o.z = fmaxf(o.z, 0.f); o.w = fmaxf(o.w, 0.f);
    }
    *reinterpret_cast<float4*>(&C[(size_t)(m0 + ty * 8 + i) * Nn + n0 + tx * 4]) = o;
  }
}

// ---------------------------------------------------------------- Conv1d k=3 pad=1
// Out[m, o] = sum_tap sum_i X[m-1+tap, i] * Wc[o, i, tap] + bc[o], per-batch zero pad.
__global__ __launch_bounds__(256, 2) void conv3_kernel(
    const float* __restrict__ X, const float* __restrict__ Wc,
    const float* __restrict__ bc, float* __restrict__ Out)
{
  constexpr int BM = 128, BN = 64, BK = 16;
  __shared__ float As[BK][BM + 8];       // rows m0-1 .. m0+128 (130 used)
  __shared__ float Bs[3][BK][BN + 4];    // Bs[tap][k][o]
  const int tid = threadIdx.x;
  const int tx = tid & 15, ty = tid >> 4;
  const int m0 = blockIdx.x * BM, n0 = blockIdx.y * BN;
  const int blo = (m0 / kT) * kT, bhi = blo + kT;

  float acc[8][4];
#pragma unroll
  for (int i = 0; i < 8; ++i)
#pragma unroll
    for (int j = 0; j < 4; ++j) acc[i][j] = 0.f;

  for (int k0 = 0; k0 < kD; k0 += BK) {
    for (int f = tid; f < 520; f += 256) {   // 130 rows x 16 = 520 float4
      int rr = f >> 2, c4 = (f & 3) * 4;
      int g = m0 - 1 + rr;
      float4 v = {0.f, 0.f, 0.f, 0.f};
      if (g >= blo && g < bhi)
        v = *reinterpret_cast<const float4*>(&X[(size_t)g * kD + k0 + c4]);
      As[c4 + 0][rr] = v.x; As[c4 + 1][rr] = v.y;
      As[c4 + 2][rr] = v.z; As[c4 + 3][rr] = v.w;
    }
    for (int f = tid; f < 3072; f += 256) {  // 64 ch x 16 k x 3 taps
      int o = f / 48, r = f - o * 48, kk = r / 3, tap = r - kk * 3;
      Bs[tap][kk][o] = Wc[(size_t)(n0 + o) * (kD * 3) + (size_t)(k0 + kk) * 3 + tap];
    }
    __syncthreads();
#pragma unroll
    for (int kk = 0; kk < BK; ++kk) {
      float4 A0 = *reinterpret_cast<const float4*>(&As[kk][ty * 8]);
      float4 A1 = *reinterpret_cast<const float4*>(&As[kk][ty * 8 + 4]);
      float4 A2 = *reinterpret_cast<const float4*>(&As[kk][ty * 8 + 8]);
      float a[12] = {A0.x, A0.y, A0.z, A0.w, A1.x, A1.y, A1.z, A1.w,
                     A2.x, A2.y, A2.z, A2.w};
      float b[3][4];
#pragma unroll
      for (int tp = 0; tp < 3; ++tp) {
        float4 bb = *reinterpret_cast<const float4*>(&Bs[tp][kk][tx * 4]);
        b[tp][0] = bb.x; b[tp][1] = bb.y; b[tp][2] = bb.z; b[tp][3] = bb.w;
      }
#pragma unroll
      for (int i = 0; i < 8; ++i)
#pragma unroll
        for (int j = 0; j < 4; ++j)
          acc[i][j] += a[i] * b[0][j] + a[i + 1] * b[1][j] + a[i + 2] * b[2][j];
    }
    __syncthreads();
  }

  float bv[4];
#pragma unroll
  for (int j = 0; j < 4; ++j) bv[j] = bc[n0 + tx * 4 + j];
#pragma unroll
  for (int i = 0; i < 8; ++i) {
    float4 o;
    o.x = acc[i][0] + bv[0]; o.y = acc[i][1] + bv[1];
    o.z = acc[i][2] + bv[2]; o.w = acc[i][3] + bv[3];
    *reinterpret_cast<float4*>(&Out[(size_t)(m0 + ty * 8 + i) * kD + n0 + tx * 4]) = o;
  }
}

// ---------------------------------------------------------------- banded attention
// QK: [N,1024] (cols 0..511 = q, 512..1023 = k), V: [N,512], Ctx: [N,512]
// scores = q.k/8, mask |i-j|<=256, softmax, ctx = P@V. Block: (b,h,16 rows).
__global__ __launch_bounds__(256) void attn_kernel(
    const float* __restrict__ QK, const float* __restrict__ V,
    float* __restrict__ Ctx)
{
  constexpr int RB = 16;
  constexpr int MAXT = 9;
  __shared__ float S[RB][MAXT * 64 + 1];   // [16][577]
  __shared__ float Qs[RB][64 + 4];
  __shared__ float KV[64][64 + 4];
  const int tid = threadIdx.x;
  const int bh = blockIdx.y;
  const int b = bh >> 3, h = bh & 7;
  const int r0 = blockIdx.x * RB;
  const int rowbase = b * kT;
  const int t_lo = max(r0 - 256, 0) & ~63;
  const int t_hi = min(r0 + RB - 1 + 256, kT - 1);
  const int ntiles = ((t_hi - t_lo) >> 6) + 1;   // <= 9

  {  // stage Q: 16 x 64 = 256 float4, one per thread
    int rr = tid >> 4, d4 = (tid & 15) * 4;
    float4 v = *reinterpret_cast<const float4*>(
        &QK[(size_t)(rowbase + r0 + rr) * 1024 + h * 64 + d4]);
    *reinterpret_cast<float4*>(&Qs[rr][d4]) = v;
  }
  __syncthreads();

  const int row = tid >> 4;   // 0..15
  const int lg  = tid & 15;   // 0..15
  const int qrow = r0 + row;

  float q[64];
#pragma unroll
  for (int d4 = 0; d4 < 64; d4 += 4) {
    float4 v = *reinterpret_cast<const float4*>(&Qs[row][d4]);
    q[d4] = v.x; q[d4 + 1] = v.y; q[d4 + 2] = v.z; q[d4 + 3] = v.w;
  }

  // phase 1: S = q.k/8 with band mask
  for (int tt = 0; tt < ntiles; ++tt) {
    const int j0 = t_lo + tt * 64;
    __syncthreads();
#pragma unroll
    for (int i = 0; i < 4; ++i) {       // stage K tile 64x64
      int f = tid + 256 * i;
      int rr = f >> 4, d4 = (f & 15) * 4;
      float4 v = *reinterpret_cast<const float4*>(
          &QK[(size_t)(rowbase + j0 + rr) * 1024 + 512 + h * 64 + d4]);
      *reinterpret_cast<float4*>(&KV[rr][d4]) = v;
    }
    __syncthreads();
#pragma unroll
    for (int u = 0; u < 4; ++u) {
      int jj = lg + 16 * u;
      int j = j0 + jj;
      float s = 0.f;
#pragma unroll
      for (int d4 = 0; d4 < 64; d4 += 4) {
        float4 kv = *reinterpret_cast<const float4*>(&KV[jj][d4]);
        s = fmaf(q[d4], kv.x, s);     s = fmaf(q[d4 + 1], kv.y, s);
        s = fmaf(q[d4 + 2], kv.z, s); s = fmaf(q[d4 + 3], kv.w, s);
      }
      bool ok = (j >= qrow - 256) && (j <= qrow + 256);
      S[row][tt * 64 + jj] = ok ? s * 0.125f : kNegInf;
    }
  }
  __syncthreads();

  // phase 2: softmax over the band, 16 threads per row
  {
    const int n = ntiles * 64;
    float m = kNegInf;
    for (int c = lg; c < n; c += 16) m = fmaxf(m, S[row][c]);
#pragma unroll
    for (int o = 1; o < 16; o <<= 1) m = fmaxf(m, __shfl_xor(m, o, 64));
    float l = 0.f;
    for (int c = lg; c < n; c += 16) {
      float p = __expf(S[row][c] - m);
      S[row][c] = p; l += p;
    }
#pragma unroll
    for (int o = 1; o < 16; o <<= 1) l += __shfl_xor(l, o, 64);
    float inv = 1.0f / l;
    for (int c = lg; c < n; c += 16) S[row][c] *= inv;
  }

  // phase 3: ctx = P @ V
  float a4[4] = {0.f, 0.f, 0.f, 0.f};
  for (int tt = 0; tt < ntiles; ++tt) {
    const int j0 = t_lo + tt * 64;
    __syncthreads();
#pragma unroll
    for (int i = 0; i < 4; ++i) {       // stage V tile 64x64
      int f = tid + 256 * i;
      int rr = f >> 4, d4 = (f & 15) * 4;
      float4 v = *reinterpret_cast<const float4*>(
          &V[(size_t)(rowbase + j0 + rr) * 512 + h * 64 + d4]);
      *reinterpret_cast<float4*>(&KV[rr][d4]) = v;
    }
    __syncthreads();
    for (int jj = 0; jj < 64; ++jj) {
      float p = S[row][tt * 64 + jj];
      float4 v = *reinterpret_cast<const float4*>(&KV[jj][lg * 4]);
      a4[0] = fmaf(p, v.x, a4[0]); a4[1] = fmaf(p, v.y, a4[1]);
      a4[2] = fmaf(p, v.z, a4[2]); a4[3] = fmaf(p, v.w, a4[3]);
    }
  }
  float4 o = {a4[0], a4[1], a4[2], a4[3]};
  *reinterpret_cast<float4*>(
      &Ctx[(size_t)(rowbase + r0 + row) * 512 + h * 64 + lg * 4]) = o;
}

// ---------------------------------------------------------------- residual + LayerNorm
// Out[row] = LN(A[row] + Bq[row]) * G + Bt. One wave per row, 4 rows/block.
__global__ __launch_bounds__(256) void ln_kernel(
    const float* __restrict__ A, const float* __restrict__ Bq,
    const float* __restrict__ G, const float* __restrict__ Bt,
    float* __restrict__ Out)
{
  const int lane = threadIdx.x & 63;
  const int wv = threadIdx.x >> 6;
  const int row = blockIdx.x * 4 + wv;
  const size_t base = (size_t)row * kD + lane * 8;

  float4 a0 = *reinterpret_cast<const float4*>(&A[base]);
  float4 a1 = *reinterpret_cast<const float4*>(&A[base + 4]);
  float4 b0 = *reinterpret_cast<const float4*>(&Bq[base]);
  float4 b1 = *reinterpret_cast<const float4*>(&Bq[base + 4]);
  float x[8] = {a0.x + b0.x, a0.y + b0.y, a0.z + b0.z, a0.w + b0.w,
                a1.x + b1.x, a1.y + b1.y, a1.z + b1.z, a1.w + b1.w};
  float s = 0.f, ss = 0.f;
#pragma unroll
  for (int i = 0; i < 8; ++i) { s += x[i]; ss += x[i] * x[i]; }
#pragma unroll
  for (int o = 1; o < 64; o <<= 1) {
    s += __shfl_xor(s, o, 64);
    ss += __shfl_xor(ss, o, 64);
  }
  const float mean = s * (1.f / kD);
  const float var = ss * (1.f / kD) - mean * mean;
  const float rs = rsqrtf(var + 1e-5f);

  const int c = lane * 8;
  float4 g0 = *reinterpret_cast<const float4*>(&G[c]);
  float4 g1 = *reinterpret_cast<const float4*>(&G[c + 4]);
  float4 t0 = *reinterpret_cast<const float4*>(&Bt[c]);
  float4 t1 = *reinterpret_cast<const float4*>(&Bt[c + 4]);
  float4 o0, o1;
  o0.x = (x[0] - mean) * rs * g0.x + t0.x;
  o0.y = (x[1] - mean) * rs * g0.y + t0.y;
  o0.z = (x[2] - mean) * rs * g0.z + t0.z;
  o0.w = (x[3] - mean) * rs * g0.w + t0.w;
  o1.x = (x[4] - mean) * rs * g1.x + t1.x;
  o1.y = (x[5] - mean) * rs * g1.y + t1.y;
  o1.z = (x[6] - mean) * rs * g1.z + t1.z;
  o1.w = (x[7] - mean) * rs * g1.w + t1.w;
  *reinterpret_cast<float4*>(&Out[base]) = o0;
  *reinterpret_cast<float4*>(&Out[base + 4]) = o1;
}

// ---------------------------------------------------------------- launch
extern "C" void kernel_launch(void* const* d_in, const int* in_sizes, int n_in,
                              void* d_out, int out_size, void* d_ws, size_t ws_size,
                              hipStream_t stream)
{
  const float* x   = (const float*)d_in[0];
  // d_in[1] = pe is unused by the reference
  const float* cw  = (const float*)d_in[2];
  const float* cb  = (const float*)d_in[3];
  const float* ipw = (const float*)d_in[4];
  const float* ipb = (const float*)d_in[5];
  const float* opw = (const float*)d_in[6];
  const float* opb = (const float*)d_in[7];
  const float* g1  = (const float*)d_in[8];
  const float* b1n = (const float*)d_in[9];
  const float* w1  = (const float*)d_in[10];
  const float* bb1 = (const float*)d_in[11];
  const float* w2  = (const float*)d_in[12];
  const float* bb2 = (const float*)d_in[13];
  const float* g2  = (const float*)d_in[14];
  const float* b2n = (const float*)d_in[15];
  float* out = (float*)d_out;

  float* ws = (float*)d_ws;
  const size_t ND = (size_t)kN * kD;
  float* vin  = ws;              // [N,512] conv output
  float* qk   = vin + ND;        // [N,1024] q|k
  float* vbuf = qk + 2 * ND;     // [N,512] v
  float* ctx  = vbuf + ND;       // [N,512]
  float* hbuf = ctx + ND;        // [N,512]
  float* attn = vin;             // reuse (vin dead after v-proj)
  float* f1   = qk;              // reuse (qk dead after attention)
  float* f2   = ctx;             // reuse (ctx dead after out-proj)

  dim3 blk(256);
  // conv1d on values
  conv3_kernel<<<dim3(kN / 128, kD / 64), blk, 0, stream>>>(x, cw, cb, vin);
  // q,k projection (rows 0..1023 of in_proj)
  gemm_kernel<<<dim3(kN / 128, 1024 / 64), blk, 0, stream>>>(
      x, ipw, ipb, qk, kN, 1024, kD, 0);
  // v projection (rows 1024..1535 of in_proj) from conv output
  gemm_kernel<<<dim3(kN / 128, 512 / 64), blk, 0, stream>>>(
      vin, ipw + (size_t)1024 * kD, ipb + 1024, vbuf, kN, 512, kD, 0);
  // banded attention
  attn_kernel<<<dim3(kT / 16, kB * 8), blk, 0, stream>>>(qk, vbuf, ctx);
  // out projection
  gemm_kernel<<<dim3(kN / 128, 512 / 64), blk, 0, stream>>>(
      ctx, opw, opb, attn, kN, 512, kD, 0);
  // h = LN(x + attn_out)
  ln_kernel<<<dim3(kN / 4), blk, 0, stream>>>(x, attn, g1, b1n, hbuf);
  // ffn1 = relu(h @ w1^T + b1)
  gemm_kernel<<<dim3(kN / 128, 1024 / 64), blk, 0, stream>>>(
      hbuf, w1, bb1, f1, kN, 1024, kD, 1);
  // ffn2 = ffn1 @ w2^T + b2
  gemm_kernel<<<dim3(kN / 128, 512 / 64), blk, 0, stream>>>(
      f1, w2, bb2, f2, kN, 512, 1024, 0);
  // out = LN(h + ffn2)
  ln_kernel<<<dim3(kN / 4), blk, 0, stream>>>(hbuf, f2, g2, b2n, out);
}

// Round 2
// 465.093 us; speedup vs baseline: 2.1773x; 2.1773x over previous
//
#include <hip/hip_runtime.h>
#include <cstdint>
#include <cstddef>

static constexpr int kT  = 2048;
static constexpr int kD  = 512;
static constexpr int kB  = 2;
static constexpr int kN  = kB * kT;   // 4096 rows
static constexpr float kNegInf = -1e30f;

using short8 = __attribute__((ext_vector_type(8))) short;
using f32x4  = __attribute__((ext_vector_type(4))) float;
typedef unsigned short ushort;

__device__ inline ushort f2bf(float f) {
  uint32_t u = __builtin_bit_cast(uint32_t, f);
  uint32_t r = (u + 0x7FFFu + ((u >> 16) & 1u)) >> 16;
  return (ushort)r;
}

#define GLOAD_LDS16(g, l)                                         \
  __builtin_amdgcn_global_load_lds(                               \
      (const __attribute__((address_space(1))) void*)(g),         \
      (__attribute__((address_space(3))) void*)(l), 16, 0, 0)

// ---------------------------------------------------------------- casts
__global__ __launch_bounds__(256) void cast_kernel(
    const float* __restrict__ in, ushort* __restrict__ out, int n4)
{
  for (int t = blockIdx.x * 256 + threadIdx.x; t < n4; t += gridDim.x * 256) {
    float4 v = *reinterpret_cast<const float4*>(&in[(size_t)t * 4]);
    ushort o[4] = {f2bf(v.x), f2bf(v.y), f2bf(v.z), f2bf(v.w)};
    *reinterpret_cast<uint2*>(&out[(size_t)t * 4]) =
        *reinterpret_cast<uint2*>(o);
  }
}

// W_cat[o][tap*512 + i] = conv_w[o][i][tap]
__global__ __launch_bounds__(256) void convw_kernel(
    const float* __restrict__ cw, ushort* __restrict__ wcat)
{
  for (int t = blockIdx.x * 256 + threadIdx.x; t < kD * kD;
       t += gridDim.x * 256) {
    int o = t >> 9, i = t & 511;
    const float* src = &cw[(size_t)(o * kD + i) * 3];
    ushort* dst = &wcat[(size_t)o * (3 * kD) + i];
#pragma unroll
    for (int tap = 0; tap < 3; ++tap) dst[tap * kD] = f2bf(src[tap]);
  }
}

// A_cat[m][tap*512 + i8*8 ..+8] = xb[m+tap-1][i8*8..] (0 at batch edges)
__global__ __launch_bounds__(256) void acat_kernel(
    const ushort* __restrict__ xb, ushort* __restrict__ acat)
{
  const int total = kN * 3 * 64;
  for (int t = blockIdx.x * 256 + threadIdx.x; t < total;
       t += gridDim.x * 256) {
    int m = t / 192, r = t - m * 192;
    int tap = r >> 6, i8 = r & 63;
    int tib = (m & (kT - 1)) + tap - 1;
    uint4 v = {0u, 0u, 0u, 0u};
    if (tib >= 0 && tib < kT)
      v = *reinterpret_cast<const uint4*>(&xb[(size_t)(m + tap - 1) * kD + i8 * 8]);
    *reinterpret_cast<uint4*>(&acat[(size_t)m * (3 * kD) + tap * kD + i8 * 8]) = v;
  }
}

// ---------------------------------------------------------------- MFMA GEMM
// C[M,Nn] = A[M,K] @ W[Nn,K]^T + bias. A,W bf16 row-major; OutT float/ushort.
// 128x128 tile, BK=32, 256 threads = 4 waves (2x2), wave does 64x64.
template <typename OutT, int RELU>
__global__ __launch_bounds__(256) void gemm_bf16(
    const ushort* __restrict__ A, const ushort* __restrict__ W,
    const float* __restrict__ bias, OutT* __restrict__ C,
    int M, int Nn, int K)
{
  __shared__ __align__(16) ushort As[128 * 32];
  __shared__ __align__(16) ushort Bs[128 * 32];
  const int tid = threadIdx.x;
  const int lane = tid & 63, w = tid >> 6;
  const int wr = w >> 1, wc = w & 1;
  const int m0 = blockIdx.x * 128, n0 = blockIdx.y * 128;

  f32x4 acc[4][4];
#pragma unroll
  for (int i = 0; i < 4; ++i)
#pragma unroll
    for (int j = 0; j < 4; ++j) acc[i][j] = {0.f, 0.f, 0.f, 0.f};

  // per-lane global source offsets for staging (lane covers 16B)
  const int srow = lane >> 2;        // 0..15 within 16-row chunk
  const int scol = (lane & 3) * 8;   // 8 bf16 = 16B
  const int c0 = w * 2, c1 = w * 2 + 1;

  for (int k0 = 0; k0 < K; k0 += 32) {
    const ushort* gA0 = A + (size_t)(m0 + c0 * 16 + srow) * K + k0 + scol;
    const ushort* gA1 = A + (size_t)(m0 + c1 * 16 + srow) * K + k0 + scol;
    const ushort* gB0 = W + (size_t)(n0 + c0 * 16 + srow) * K + k0 + scol;
    const ushort* gB1 = W + (size_t)(n0 + c1 * 16 + srow) * K + k0 + scol;
    GLOAD_LDS16(gA0, &As[c0 * 512]);
    GLOAD_LDS16(gA1, &As[c1 * 512]);
    GLOAD_LDS16(gB0, &Bs[c0 * 512]);
    GLOAD_LDS16(gB1, &Bs[c1 * 512]);
    __syncthreads();

    const int fr = lane & 15;         // fragment row within 16
    const int fk = (lane >> 4) * 8;   // k-offset (8 bf16)
    short8 a[4], b[4];
#pragma unroll
    for (int m = 0; m < 4; ++m)
      a[m] = *reinterpret_cast<const short8*>(
          &As[(wr * 64 + m * 16 + fr) * 32 + fk]);
#pragma unroll
    for (int n = 0; n < 4; ++n)
      b[n] = *reinterpret_cast<const short8*>(
          &Bs[(wc * 64 + n * 16 + fr) * 32 + fk]);
#pragma unroll
    for (int m = 0; m < 4; ++m)
#pragma unroll
      for (int n = 0; n < 4; ++n)
        acc[m][n] = __builtin_amdgcn_mfma_f32_16x16x32_bf16(
            a[m], b[n], acc[m][n], 0, 0, 0);
    __syncthreads();
  }

  const int fq = lane >> 4;   // row group
  const int fr = lane & 15;   // col within 16
  float bv[4];
#pragma unroll
  for (int n = 0; n < 4; ++n) bv[n] = bias[n0 + wc * 64 + n * 16 + fr];
#pragma unroll
  for (int m = 0; m < 4; ++m) {
#pragma unroll
    for (int j = 0; j < 4; ++j) {
      int row = m0 + wr * 64 + m * 16 + fq * 4 + j;
#pragma unroll
      for (int n = 0; n < 4; ++n) {
        int col = n0 + wc * 64 + n * 16 + fr;
        float v = acc[m][n][j] + bv[n];
        if (RELU) v = fmaxf(v, 0.f);
        if constexpr (sizeof(OutT) == 2)
          C[(size_t)row * Nn + col] = (OutT)f2bf(v);
        else
          C[(size_t)row * Nn + col] = (OutT)v;
      }
    }
  }
}

// ---------------------------------------------------------------- banded attention (fp32)
// QK: [N,1024] (q | k), V: [N,512] fp32, Ctx: [N,512] bf16 out.
__global__ __launch_bounds__(256) void attn_kernel(
    const float* __restrict__ QK, const float* __restrict__ V,
    ushort* __restrict__ Ctx)
{
  constexpr int RB = 16;
  constexpr int MAXT = 9;
  __shared__ float S[RB][MAXT * 64 + 1];
  __shared__ float Qs[RB][64 + 4];
  __shared__ float KV[64][64 + 4];
  const int tid = threadIdx.x;
  const int bh = blockIdx.y;
  const int b = bh >> 3, h = bh & 7;
  const int r0 = blockIdx.x * RB;
  const int rowbase = b * kT;
  const int t_lo = max(r0 - 256, 0) & ~63;
  const int t_hi = min(r0 + RB - 1 + 256, kT - 1);
  const int ntiles = ((t_hi - t_lo) >> 6) + 1;

  {
    int rr = tid >> 4, d4 = (tid & 15) * 4;
    float4 v = *reinterpret_cast<const float4*>(
        &QK[(size_t)(rowbase + r0 + rr) * 1024 + h * 64 + d4]);
    *reinterpret_cast<float4*>(&Qs[rr][d4]) = v;
  }
  __syncthreads();

  const int row = tid >> 4;
  const int lg  = tid & 15;
  const int qrow = r0 + row;

  float q[64];
#pragma unroll
  for (int d4 = 0; d4 < 64; d4 += 4) {
    float4 v = *reinterpret_cast<const float4*>(&Qs[row][d4]);
    q[d4] = v.x; q[d4 + 1] = v.y; q[d4 + 2] = v.z; q[d4 + 3] = v.w;
  }

  for (int tt = 0; tt < ntiles; ++tt) {
    const int j0 = t_lo + tt * 64;
    __syncthreads();
#pragma unroll
    for (int i = 0; i < 4; ++i) {
      int f = tid + 256 * i;
      int rr = f >> 4, d4 = (f & 15) * 4;
      float4 v = *reinterpret_cast<const float4*>(
          &QK[(size_t)(rowbase + j0 + rr) * 1024 + 512 + h * 64 + d4]);
      *reinterpret_cast<float4*>(&KV[rr][d4]) = v;
    }
    __syncthreads();
#pragma unroll
    for (int u = 0; u < 4; ++u) {
      int jj = lg + 16 * u;
      int j = j0 + jj;
      float s = 0.f;
#pragma unroll
      for (int d4 = 0; d4 < 64; d4 += 4) {
        float4 kv = *reinterpret_cast<const float4*>(&KV[jj][d4]);
        s = fmaf(q[d4], kv.x, s);     s = fmaf(q[d4 + 1], kv.y, s);
        s = fmaf(q[d4 + 2], kv.z, s); s = fmaf(q[d4 + 3], kv.w, s);
      }
      bool ok = (j >= qrow - 256) && (j <= qrow + 256);
      S[row][tt * 64 + jj] = ok ? s * 0.125f : kNegInf;
    }
  }
  __syncthreads();

  {
    const int n = ntiles * 64;
    float m = kNegInf;
    for (int c = lg; c < n; c += 16) m = fmaxf(m, S[row][c]);
#pragma unroll
    for (int o = 1; o < 16; o <<= 1) m = fmaxf(m, __shfl_xor(m, o, 64));
    float l = 0.f;
    for (int c = lg; c < n; c += 16) {
      float p = __expf(S[row][c] - m);
      S[row][c] = p; l += p;
    }
#pragma unroll
    for (int o = 1; o < 16; o <<= 1) l += __shfl_xor(l, o, 64);
    float inv = 1.0f / l;
    for (int c = lg; c < n; c += 16) S[row][c] *= inv;
  }

  float a4[4] = {0.f, 0.f, 0.f, 0.f};
  for (int tt = 0; tt < ntiles; ++tt) {
    const int j0 = t_lo + tt * 64;
    __syncthreads();
#pragma unroll
    for (int i = 0; i < 4; ++i) {
      int f = tid + 256 * i;
      int rr = f >> 4, d4 = (f & 15) * 4;
      float4 v = *reinterpret_cast<const float4*>(
          &V[(size_t)(rowbase + j0 + rr) * 512 + h * 64 + d4]);
      *reinterpret_cast<float4*>(&KV[rr][d4]) = v;
    }
    __syncthreads();
    for (int jj = 0; jj < 64; ++jj) {
      float p = S[row][tt * 64 + jj];
      float4 v = *reinterpret_cast<const float4*>(&KV[jj][lg * 4]);
      a4[0] = fmaf(p, v.x, a4[0]); a4[1] = fmaf(p, v.y, a4[1]);
      a4[2] = fmaf(p, v.z, a4[2]); a4[3] = fmaf(p, v.w, a4[3]);
    }
  }
  ushort o4[4] = {f2bf(a4[0]), f2bf(a4[1]), f2bf(a4[2]), f2bf(a4[3])};
  *reinterpret_cast<uint2*>(
      &Ctx[(size_t)(rowbase + r0 + row) * 512 + h * 64 + lg * 4]) =
      *reinterpret_cast<uint2*>(o4);
}

// ---------------------------------------------------------------- residual + LayerNorm
__global__ __launch_bounds__(256) void ln_kernel(
    const float* __restrict__ A, const float* __restrict__ Bq,
    const float* __restrict__ G, const float* __restrict__ Bt,
    float* __restrict__ Out, ushort* __restrict__ OutB)
{
  const int lane = threadIdx.x & 63;
  const int wv = threadIdx.x >> 6;
  const int row = blockIdx.x * 4 + wv;
  const size_t base = (size_t)row * kD + lane * 8;

  float4 a0 = *reinterpret_cast<const float4*>(&A[base]);
  float4 a1 = *reinterpret_cast<const float4*>(&A[base + 4]);
  float4 b0 = *reinterpret_cast<const float4*>(&Bq[base]);
  float4 b1 = *reinterpret_cast<const float4*>(&Bq[base + 4]);
  float x[8] = {a0.x + b0.x, a0.y + b0.y, a0.z + b0.z, a0.w + b0.w,
                a1.x + b1.x, a1.y + b1.y, a1.z + b1.z, a1.w + b1.w};
  float s = 0.f, ss = 0.f;
#pragma unroll
  for (int i = 0; i < 8; ++i) { s += x[i]; ss += x[i] * x[i]; }
#pragma unroll
  for (int o = 1; o < 64; o <<= 1) {
    s += __shfl_xor(s, o, 64);
    ss += __shfl_xor(ss, o, 64);
  }
  const float mean = s * (1.f / kD);
  const float var = ss * (1.f / kD) - mean * mean;
  const float rs = rsqrtf(var + 1e-5f);

  const int c = lane * 8;
  float4 g0 = *reinterpret_cast<const float4*>(&G[c]);
  float4 g1 = *reinterpret_cast<const float4*>(&G[c + 4]);
  float4 t0 = *reinterpret_cast<const float4*>(&Bt[c]);
  float4 t1 = *reinterpret_cast<const float4*>(&Bt[c + 4]);
  float y[8];
  y[0] = (x[0] - mean) * rs * g0.x + t0.x;
  y[1] = (x[1] - mean) * rs * g0.y + t0.y;
  y[2] = (x[2] - mean) * rs * g0.z + t0.z;
  y[3] = (x[3] - mean) * rs * g0.w + t0.w;
  y[4] = (x[4] - mean) * rs * g1.x + t1.x;
  y[5] = (x[5] - mean) * rs * g1.y + t1.y;
  y[6] = (x[6] - mean) * rs * g1.z + t1.z;
  y[7] = (x[7] - mean) * rs * g1.w + t1.w;
  *reinterpret_cast<float4*>(&Out[base]) = {y[0], y[1], y[2], y[3]};
  *reinterpret_cast<float4*>(&Out[base + 4]) = {y[4], y[5], y[6], y[7]};
  if (OutB) {
    ushort ob[8];
#pragma unroll
    for (int i = 0; i < 8; ++i) ob[i] = f2bf(y[i]);
    *reinterpret_cast<uint4*>(&OutB[base]) = *reinterpret_cast<uint4*>(ob);
  }
}

// ---------------------------------------------------------------- launch
extern "C" void kernel_launch(void* const* d_in, const int* in_sizes, int n_in,
                              void* d_out, int out_size, void* d_ws, size_t ws_size,
                              hipStream_t stream)
{
  const float* x   = (const float*)d_in[0];
  const float* cw  = (const float*)d_in[2];
  const float* cb  = (const float*)d_in[3];
  const float* ipw = (const float*)d_in[4];
  const float* ipb = (const float*)d_in[5];
  const float* opw = (const float*)d_in[6];
  const float* opb = (const float*)d_in[7];
  const float* g1  = (const float*)d_in[8];
  const float* b1n = (const float*)d_in[9];
  const float* w1  = (const float*)d_in[10];
  const float* bb1 = (const float*)d_in[11];
  const float* w2  = (const float*)d_in[12];
  const float* bb2 = (const float*)d_in[13];
  const float* g2  = (const float*)d_in[14];
  const float* b2n = (const float*)d_in[15];
  float* out = (float*)d_out;

  char* p = (char*)d_ws;
  auto take = [&](size_t bytes) {
    char* q = p; p += (bytes + 255) & ~size_t(255); return q;
  };
  ushort* xb    = (ushort*)take((size_t)kN * kD * 2);
  char*  acat_r =          take((size_t)kN * 3 * kD * 2);
  ushort* acat  = (ushort*)acat_r;
  ushort* wcat  = (ushort*)take((size_t)kD * 3 * kD * 2);
  ushort* ipwb  = (ushort*)take((size_t)3 * kD * kD * 2);
  ushort* opwb  = (ushort*)take((size_t)kD * kD * 2);
  ushort* w1b   = (ushort*)take((size_t)2 * kD * kD * 2);
  ushort* w2b   = (ushort*)take((size_t)2 * kD * kD * 2);
  ushort* convo = (ushort*)take((size_t)kN * kD * 2);
  char*  qk_r   =          take((size_t)kN * 2 * kD * 4);
  float* qk     = (float*)qk_r;
  char*  v_r    =          take((size_t)kN * kD * 4);
  float* vbuf   = (float*)v_r;
  ushort* ctx   = (ushort*)take((size_t)kN * kD * 2);
  float* hbuf   = (float*)take((size_t)kN * kD * 4);
  ushort* hb    = (ushort*)take((size_t)kN * kD * 2);
  float* attno  = (float*)acat_r;   // acat dead after conv GEMM
  ushort* f1    = (ushort*)qk_r;    // qk dead after attention
  float* f2     = (float*)v_r;      // vbuf dead after attention

  dim3 blk(256);
  // casts
  cast_kernel<<<dim3(1024), blk, 0, stream>>>(x, xb, kN * kD / 4);
  cast_kernel<<<dim3(512), blk, 0, stream>>>(ipw, ipwb, 3 * kD * kD / 4);
  cast_kernel<<<dim3(256), blk, 0, stream>>>(opw, opwb, kD * kD / 4);
  cast_kernel<<<dim3(512), blk, 0, stream>>>(w1, w1b, 2 * kD * kD / 4);
  cast_kernel<<<dim3(512), blk, 0, stream>>>(w2, w2b, 2 * kD * kD / 4);
  convw_kernel<<<dim3(1024), blk, 0, stream>>>(cw, wcat);
  acat_kernel<<<dim3(1024), blk, 0, stream>>>(xb, acat);

  // conv as GEMM: [N,1536] x [512,1536]^T -> bf16
  gemm_bf16<ushort, 0><<<dim3(kN / 128, kD / 128), blk, 0, stream>>>(
      acat, wcat, cb, convo, kN, kD, 3 * kD);
  // q,k projection -> fp32
  gemm_bf16<float, 0><<<dim3(kN / 128, 1024 / 128), blk, 0, stream>>>(
      xb, ipwb, ipb, qk, kN, 1024, kD);
  // v projection -> fp32
  gemm_bf16<float, 0><<<dim3(kN / 128, kD / 128), blk, 0, stream>>>(
      convo, ipwb + (size_t)1024 * kD, ipb + 1024, vbuf, kN, kD, kD);
  // banded attention -> bf16 ctx
  attn_kernel<<<dim3(kT / 16, kB * 8), blk, 0, stream>>>(qk, vbuf, ctx);
  // out projection -> fp32
  gemm_bf16<float, 0><<<dim3(kN / 128, kD / 128), blk, 0, stream>>>(
      ctx, opwb, opb, attno, kN, kD, kD);
  // h = LN(x + attn_out) -> fp32 + bf16
  ln_kernel<<<dim3(kN / 4), blk, 0, stream>>>(x, attno, g1, b1n, hbuf, hb);
  // ffn1 = relu(h @ w1^T + b1) -> bf16
  gemm_bf16<ushort, 1><<<dim3(kN / 128, 1024 / 128), blk, 0, stream>>>(
      hb, w1b, bb1, f1, kN, 1024, kD);
  // ffn2 -> fp32
  gemm_bf16<float, 0><<<dim3(kN / 128, kD / 128), blk, 0, stream>>>(
      f1, w2b, bb2, f2, kN, kD, 2 * kD);
  // out = LN(h + ffn2)
  ln_kernel<<<dim3(kN / 4), blk, 0, stream>>>(hbuf, f2, g2, b2n, out, nullptr);
}

// Round 3
// 263.813 us; speedup vs baseline: 3.8384x; 1.7630x over previous
//
#include <hip/hip_runtime.h>
#include <cstdint>
#include <cstddef>

static constexpr int kT  = 2048;
static constexpr int kD  = 512;
static constexpr int kB  = 2;
static constexpr int kN  = kB * kT;   // 4096 rows

using short8 = __attribute__((ext_vector_type(8))) short;
using f32x4  = __attribute__((ext_vector_type(4))) float;
typedef unsigned short ushort;

__device__ inline ushort f2bf(float f) {
  uint32_t u = __builtin_bit_cast(uint32_t, f);
  uint32_t r = (u + 0x7FFFu + ((u >> 16) & 1u)) >> 16;
  return (ushort)r;
}

#define GLOAD_LDS16(g, l)                                         \
  __builtin_amdgcn_global_load_lds(                               \
      (const __attribute__((address_space(1))) void*)(g),         \
      (__attribute__((address_space(3))) void*)(l), 16, 0, 0)

// ---------------------------------------------------------------- casts
__global__ __launch_bounds__(256) void cast_kernel(
    const float* __restrict__ in, ushort* __restrict__ out, int n4)
{
  for (int t = blockIdx.x * 256 + threadIdx.x; t < n4; t += gridDim.x * 256) {
    float4 v = *reinterpret_cast<const float4*>(&in[(size_t)t * 4]);
    ushort o[4] = {f2bf(v.x), f2bf(v.y), f2bf(v.z), f2bf(v.w)};
    *reinterpret_cast<uint2*>(&out[(size_t)t * 4]) =
        *reinterpret_cast<uint2*>(o);
  }
}

// W_cat[o][tap*512 + i] = conv_w[o][i][tap]
__global__ __launch_bounds__(256) void convw_kernel(
    const float* __restrict__ cw, ushort* __restrict__ wcat)
{
  for (int t = blockIdx.x * 256 + threadIdx.x; t < kD * kD;
       t += gridDim.x * 256) {
    int o = t >> 9, i = t & 511;
    const float* src = &cw[(size_t)(o * kD + i) * 3];
    ushort* dst = &wcat[(size_t)o * (3 * kD) + i];
#pragma unroll
    for (int tap = 0; tap < 3; ++tap) dst[tap * kD] = f2bf(src[tap]);
  }
}

// A_cat[m][tap*512 + i8*8 ..+8] = xb[m+tap-1][i8*8..] (0 at batch edges)
__global__ __launch_bounds__(256) void acat_kernel(
    const ushort* __restrict__ xb, ushort* __restrict__ acat)
{
  const int total = kN * 3 * 64;
  for (int t = blockIdx.x * 256 + threadIdx.x; t < total;
       t += gridDim.x * 256) {
    int m = t / 192, r = t - m * 192;
    int tap = r >> 6, i8 = r & 63;
    int tib = (m & (kT - 1)) + tap - 1;
    uint4 v = {0u, 0u, 0u, 0u};
    if (tib >= 0 && tib < kT)
      v = *reinterpret_cast<const uint4*>(&xb[(size_t)(m + tap - 1) * kD + i8 * 8]);
    *reinterpret_cast<uint4*>(&acat[(size_t)m * (3 * kD) + tap * kD + i8 * 8]) = v;
  }
}

// ---------------------------------------------------------------- MFMA GEMM
// C[M,Nn] = A[M,K] @ W[Nn,K]^T + bias. A,W bf16 row-major; OutT float/ushort.
template <typename OutT, int RELU>
__global__ __launch_bounds__(256) void gemm_bf16(
    const ushort* __restrict__ A, const ushort* __restrict__ W,
    const float* __restrict__ bias, OutT* __restrict__ C,
    int M, int Nn, int K)
{
  __shared__ __align__(16) ushort As[128 * 32];
  __shared__ __align__(16) ushort Bs[128 * 32];
  const int tid = threadIdx.x;
  const int lane = tid & 63, w = tid >> 6;
  const int wr = w >> 1, wc = w & 1;
  const int m0 = blockIdx.x * 128, n0 = blockIdx.y * 128;

  f32x4 acc[4][4];
#pragma unroll
  for (int i = 0; i < 4; ++i)
#pragma unroll
    for (int j = 0; j < 4; ++j) acc[i][j] = {0.f, 0.f, 0.f, 0.f};

  const int srow = lane >> 2;
  const int scol = (lane & 3) * 8;
  const int c0 = w * 2, c1 = w * 2 + 1;

  for (int k0 = 0; k0 < K; k0 += 32) {
    const ushort* gA0 = A + (size_t)(m0 + c0 * 16 + srow) * K + k0 + scol;
    const ushort* gA1 = A + (size_t)(m0 + c1 * 16 + srow) * K + k0 + scol;
    const ushort* gB0 = W + (size_t)(n0 + c0 * 16 + srow) * K + k0 + scol;
    const ushort* gB1 = W + (size_t)(n0 + c1 * 16 + srow) * K + k0 + scol;
    GLOAD_LDS16(gA0, &As[c0 * 512]);
    GLOAD_LDS16(gA1, &As[c1 * 512]);
    GLOAD_LDS16(gB0, &Bs[c0 * 512]);
    GLOAD_LDS16(gB1, &Bs[c1 * 512]);
    __syncthreads();

    const int fr = lane & 15;
    const int fk = (lane >> 4) * 8;
    short8 a[4], b[4];
#pragma unroll
    for (int m = 0; m < 4; ++m)
      a[m] = *reinterpret_cast<const short8*>(
          &As[(wr * 64 + m * 16 + fr) * 32 + fk]);
#pragma unroll
    for (int n = 0; n < 4; ++n)
      b[n] = *reinterpret_cast<const short8*>(
          &Bs[(wc * 64 + n * 16 + fr) * 32 + fk]);
#pragma unroll
    for (int m = 0; m < 4; ++m)
#pragma unroll
      for (int n = 0; n < 4; ++n)
        acc[m][n] = __builtin_amdgcn_mfma_f32_16x16x32_bf16(
            a[m], b[n], acc[m][n], 0, 0, 0);
    __syncthreads();
  }

  const int fq = lane >> 4;
  const int fr = lane & 15;
  float bv[4];
#pragma unroll
  for (int n = 0; n < 4; ++n) bv[n] = bias[n0 + wc * 64 + n * 16 + fr];
#pragma unroll
  for (int m = 0; m < 4; ++m) {
#pragma unroll
    for (int j = 0; j < 4; ++j) {
      int row = m0 + wr * 64 + m * 16 + fq * 4 + j;
#pragma unroll
      for (int n = 0; n < 4; ++n) {
        int col = n0 + wc * 64 + n * 16 + fr;
        float v = acc[m][n][j] + bv[n];
        if (RELU) v = fmaxf(v, 0.f);
        if constexpr (sizeof(OutT) == 2)
          C[(size_t)row * Nn + col] = (OutT)f2bf(v);
        else
          C[(size_t)row * Nn + col] = (OutT)v;
      }
    }
  }
}

// ---------------------------------------------------------------- banded MFMA attention
// QK: [N,1024] bf16 (q | k), V: [N,512] bf16, Ctx: [N,512] bf16.
// Block: (b,h,64 q-rows), 4 waves x 16 q-rows. Flash-style over <=9 K-tiles.
__global__ __launch_bounds__(256) void attn_mfma(
    const ushort* __restrict__ QK, const ushort* __restrict__ V,
    ushort* __restrict__ Ctx)
{
  constexpr int PAD = 72;
  __shared__ __align__(16) ushort Ks[64 * 64];      // XOR-swizzled 16B units
  __shared__ __align__(16) ushort Vt[64][PAD];      // transposed V: [d][j]
  __shared__ __align__(16) ushort Pl[4][16][PAD];   // per-wave P
  const int tid = threadIdx.x;
  const int lane = tid & 63, w = tid >> 6;
  const int l15 = lane & 15, g = lane >> 4;
  const int bh = blockIdx.y;
  const int b = bh >> 3, h = bh & 7;
  const int r0 = blockIdx.x * 64;
  const int rowbase = b * kT;
  const int qrow0 = r0 + w * 16;
  const int t_lo = max(r0 - 256, 0);
  const int t_last = min(r0 + 256, kT - 64);
  const int ntiles = ((t_last - t_lo) >> 6) + 1;

  // Q fragments straight from global (row = l15, k = g*8 within 32-chunk)
  short8 qf[2];
  {
    const size_t qb = (size_t)(rowbase + qrow0 + l15) * 1024 + h * 64 + g * 8;
    qf[0] = *reinterpret_cast<const short8*>(&QK[qb]);
    qf[1] = *reinterpret_cast<const short8*>(&QK[qb + 32]);
  }

  f32x4 acc[4];
#pragma unroll
  for (int d = 0; d < 4; ++d) acc[d] = {0.f, 0.f, 0.f, 0.f};
  float mrun[4] = {-1e30f, -1e30f, -1e30f, -1e30f};
  float lrun[4] = {0.f, 0.f, 0.f, 0.f};

  for (int tt = 0; tt < ntiles; ++tt) {
    const int j0 = t_lo + tt * 64;

    // stage K tile: linear LDS dest, XOR-swizzled global source (m173)
#pragma unroll
    for (int c = 0; c < 2; ++c) {
      int u = c * 256 + tid;
      int row = u >> 3;
      int col8 = (u & 7) ^ (row & 7);
      const ushort* src =
          &QK[(size_t)(rowbase + j0 + row) * 1024 + 512 + h * 64 + col8 * 8];
      GLOAD_LDS16(src, &Ks[(c * 256 + w * 64) * 8]);
    }
    // stage V transposed via regs (wave w handles d-group w+4i)
#pragma unroll
    for (int i = 0; i < 2; ++i) {
      int dg = w + 4 * i;
      uint4 vv = *reinterpret_cast<const uint4*>(
          &V[(size_t)(rowbase + j0 + lane) * 512 + h * 64 + dg * 8]);
      ushort tmp[8];
      *reinterpret_cast<uint4*>(tmp) = vv;
#pragma unroll
      for (int e = 0; e < 8; ++e) Vt[dg * 8 + e][lane] = tmp[e];
    }
    __syncthreads();

    // S = Q @ K^T   (C-layout: row q = g*4+j, col key = n*16+l15)
    f32x4 s[4];
#pragma unroll
    for (int n = 0; n < 4; ++n) {
      f32x4 z = {0.f, 0.f, 0.f, 0.f};
#pragma unroll
      for (int kc = 0; kc < 2; ++kc) {
        int row = n * 16 + l15;
        int unit = row * 8 + ((kc * 4 + g) ^ (row & 7));
        short8 kb = *reinterpret_cast<const short8*>(&Ks[unit * 8]);
        z = __builtin_amdgcn_mfma_f32_16x16x32_bf16(qf[kc], kb, z, 0, 0, 0);
      }
      s[n] = z;
    }
    // scale + band mask
#pragma unroll
    for (int n = 0; n < 4; ++n)
#pragma unroll
      for (int j = 0; j < 4; ++j) {
        int col = j0 + n * 16 + l15;
        int qr = qrow0 + g * 4 + j;
        int dlt = col - qr;
        float v = s[n][j] * 0.125f;
        s[n][j] = (dlt > 256 || dlt < -256) ? -1e30f : v;
      }
    // online softmax update (per j-row; 16-lane reductions)
    float pn[4][4];
    float sold[4];
#pragma unroll
    for (int j = 0; j < 4; ++j) {
      float mx = fmaxf(fmaxf(s[0][j], s[1][j]), fmaxf(s[2][j], s[3][j]));
      mx = fmaxf(mx, __shfl_xor(mx, 1));
      mx = fmaxf(mx, __shfl_xor(mx, 2));
      mx = fmaxf(mx, __shfl_xor(mx, 4));
      mx = fmaxf(mx, __shfl_xor(mx, 8));
      float mnew = fmaxf(mrun[j], mx);
      float sc = __expf(mrun[j] - mnew);
      mrun[j] = mnew;
      sold[j] = sc;
      float rs = 0.f;
#pragma unroll
      for (int n = 0; n < 4; ++n) {
        float p = __expf(s[n][j] - mnew);
        pn[n][j] = p;
        rs += p;
      }
      rs += __shfl_xor(rs, 1);
      rs += __shfl_xor(rs, 2);
      rs += __shfl_xor(rs, 4);
      rs += __shfl_xor(rs, 8);
      lrun[j] = lrun[j] * sc + rs;
    }
    // rescale ctx accumulator
#pragma unroll
    for (int d = 0; d < 4; ++d)
#pragma unroll
      for (int j = 0; j < 4; ++j) acc[d][j] *= sold[j];
    // P -> bf16 -> per-wave LDS (C-layout -> A-fragment reshape)
#pragma unroll
    for (int n = 0; n < 4; ++n)
#pragma unroll
      for (int j = 0; j < 4; ++j)
        Pl[w][g * 4 + j][n * 16 + l15] = f2bf(pn[n][j]);
    asm volatile("s_waitcnt lgkmcnt(0)" ::: "memory");
    __builtin_amdgcn_sched_barrier(0);

    short8 pa[2];
    pa[0] = *reinterpret_cast<const short8*>(&Pl[w][l15][g * 8]);
    pa[1] = *reinterpret_cast<const short8*>(&Pl[w][l15][32 + g * 8]);
    // ctx += P @ V   (B operand = Vt rows = d)
#pragma unroll
    for (int d = 0; d < 4; ++d) {
#pragma unroll
      for (int kc = 0; kc < 2; ++kc) {
        short8 vb = *reinterpret_cast<const short8*>(
            &Vt[d * 16 + l15][kc * 32 + g * 8]);
        acc[d] = __builtin_amdgcn_mfma_f32_16x16x32_bf16(pa[kc], vb, acc[d], 0, 0, 0);
      }
    }
    __syncthreads();
  }

  float inv[4];
#pragma unroll
  for (int j = 0; j < 4; ++j) inv[j] = 1.f / lrun[j];
#pragma unroll
  for (int d = 0; d < 4; ++d)
#pragma unroll
    for (int j = 0; j < 4; ++j) {
      float v = acc[d][j] * inv[j];
      Ctx[(size_t)(rowbase + qrow0 + g * 4 + j) * 512 + h * 64 + d * 16 + l15] =
          f2bf(v);
    }
}

// ---------------------------------------------------------------- residual + LayerNorm
__global__ __launch_bounds__(256) void ln_kernel(
    const float* __restrict__ A, const float* __restrict__ Bq,
    const float* __restrict__ G, const float* __restrict__ Bt,
    float* __restrict__ Out, ushort* __restrict__ OutB)
{
  const int lane = threadIdx.x & 63;
  const int wv = threadIdx.x >> 6;
  const int row = blockIdx.x * 4 + wv;
  const size_t base = (size_t)row * kD + lane * 8;

  float4 a0 = *reinterpret_cast<const float4*>(&A[base]);
  float4 a1 = *reinterpret_cast<const float4*>(&A[base + 4]);
  float4 b0 = *reinterpret_cast<const float4*>(&Bq[base]);
  float4 b1 = *reinterpret_cast<const float4*>(&Bq[base + 4]);
  float x[8] = {a0.x + b0.x, a0.y + b0.y, a0.z + b0.z, a0.w + b0.w,
                a1.x + b1.x, a1.y + b1.y, a1.z + b1.z, a1.w + b1.w};
  float s = 0.f, ss = 0.f;
#pragma unroll
  for (int i = 0; i < 8; ++i) { s += x[i]; ss += x[i] * x[i]; }
#pragma unroll
  for (int o = 1; o < 64; o <<= 1) {
    s += __shfl_xor(s, o, 64);
    ss += __shfl_xor(ss, o, 64);
  }
  const float mean = s * (1.f / kD);
  const float var = ss * (1.f / kD) - mean * mean;
  const float rs = rsqrtf(var + 1e-5f);

  const int c = lane * 8;
  float4 g0 = *reinterpret_cast<const float4*>(&G[c]);
  float4 g1 = *reinterpret_cast<const float4*>(&G[c + 4]);
  float4 t0 = *reinterpret_cast<const float4*>(&Bt[c]);
  float4 t1 = *reinterpret_cast<const float4*>(&Bt[c + 4]);
  float y[8];
  y[0] = (x[0] - mean) * rs * g0.x + t0.x;
  y[1] = (x[1] - mean) * rs * g0.y + t0.y;
  y[2] = (x[2] - mean) * rs * g0.z + t0.z;
  y[3] = (x[3] - mean) * rs * g0.w + t0.w;
  y[4] = (x[4] - mean) * rs * g1.x + t1.x;
  y[5] = (x[5] - mean) * rs * g1.y + t1.y;
  y[6] = (x[6] - mean) * rs * g1.z + t1.z;
  y[7] = (x[7] - mean) * rs * g1.w + t1.w;
  *reinterpret_cast<float4*>(&Out[base]) = {y[0], y[1], y[2], y[3]};
  *reinterpret_cast<float4*>(&Out[base + 4]) = {y[4], y[5], y[6], y[7]};
  if (OutB) {
    ushort ob[8];
#pragma unroll
    for (int i = 0; i < 8; ++i) ob[i] = f2bf(y[i]);
    *reinterpret_cast<uint4*>(&OutB[base]) = *reinterpret_cast<uint4*>(ob);
  }
}

// ---------------------------------------------------------------- launch
extern "C" void kernel_launch(void* const* d_in, const int* in_sizes, int n_in,
                              void* d_out, int out_size, void* d_ws, size_t ws_size,
                              hipStream_t stream)
{
  const float* x   = (const float*)d_in[0];
  const float* cw  = (const float*)d_in[2];
  const float* cb  = (const float*)d_in[3];
  const float* ipw = (const float*)d_in[4];
  const float* ipb = (const float*)d_in[5];
  const float* opw = (const float*)d_in[6];
  const float* opb = (const float*)d_in[7];
  const float* g1  = (const float*)d_in[8];
  const float* b1n = (const float*)d_in[9];
  const float* w1  = (const float*)d_in[10];
  const float* bb1 = (const float*)d_in[11];
  const float* w2  = (const float*)d_in[12];
  const float* bb2 = (const float*)d_in[13];
  const float* g2  = (const float*)d_in[14];
  const float* b2n = (const float*)d_in[15];
  float* out = (float*)d_out;

  char* p = (char*)d_ws;
  auto take = [&](size_t bytes) {
    char* q = p; p += (bytes + 255) & ~size_t(255); return q;
  };
  ushort* xb    = (ushort*)take((size_t)kN * kD * 2);
  char*  acat_r =          take((size_t)kN * 3 * kD * 2);   // 12MB region
  ushort* acat  = (ushort*)acat_r;
  ushort* wcat  = (ushort*)take((size_t)kD * 3 * kD * 2);
  ushort* ipwb  = (ushort*)take((size_t)3 * kD * kD * 2);
  ushort* opwb  = (ushort*)take((size_t)kD * kD * 2);
  ushort* w1b   = (ushort*)take((size_t)2 * kD * kD * 2);
  ushort* w2b   = (ushort*)take((size_t)2 * kD * kD * 2);
  ushort* convo = (ushort*)take((size_t)kN * kD * 2);
  char*  qk_r   =          take((size_t)kN * 2 * kD * 2);   // 8MB, bf16 q|k
  ushort* qkb   = (ushort*)qk_r;
  ushort* vbb   = (ushort*)take((size_t)kN * kD * 2);
  ushort* ctx   = (ushort*)take((size_t)kN * kD * 2);
  float* hbuf   = (float*)take((size_t)kN * kD * 4);
  ushort* hb    = (ushort*)take((size_t)kN * kD * 2);
  float* attno  = (float*)acat_r;    // acat dead after conv GEMM
  ushort* f1    = (ushort*)qk_r;     // qkb dead after attention
  float* f2     = (float*)acat_r;    // attno dead after LN1

  dim3 blk(256);
  cast_kernel<<<dim3(1024), blk, 0, stream>>>(x, xb, kN * kD / 4);
  cast_kernel<<<dim3(512), blk, 0, stream>>>(ipw, ipwb, 3 * kD * kD / 4);
  cast_kernel<<<dim3(256), blk, 0, stream>>>(opw, opwb, kD * kD / 4);
  cast_kernel<<<dim3(512), blk, 0, stream>>>(w1, w1b, 2 * kD * kD / 4);
  cast_kernel<<<dim3(512), blk, 0, stream>>>(w2, w2b, 2 * kD * kD / 4);
  convw_kernel<<<dim3(1024), blk, 0, stream>>>(cw, wcat);
  acat_kernel<<<dim3(1024), blk, 0, stream>>>(xb, acat);

  // conv as GEMM -> bf16
  gemm_bf16<ushort, 0><<<dim3(kN / 128, kD / 128), blk, 0, stream>>>(
      acat, wcat, cb, convo, kN, kD, 3 * kD);
  // q,k projection -> bf16
  gemm_bf16<ushort, 0><<<dim3(kN / 128, 1024 / 128), blk, 0, stream>>>(
      xb, ipwb, ipb, qkb, kN, 1024, kD);
  // v projection -> bf16
  gemm_bf16<ushort, 0><<<dim3(kN / 128, kD / 128), blk, 0, stream>>>(
      convo, ipwb + (size_t)1024 * kD, ipb + 1024, vbb, kN, kD, kD);
  // banded MFMA attention -> bf16 ctx
  attn_mfma<<<dim3(kT / 64, kB * 8), blk, 0, stream>>>(qkb, vbb, ctx);
  // out projection -> fp32
  gemm_bf16<float, 0><<<dim3(kN / 128, kD / 128), blk, 0, stream>>>(
      ctx, opwb, opb, attno, kN, kD, kD);
  // h = LN(x + attn_out)
  ln_kernel<<<dim3(kN / 4), blk, 0, stream>>>(x, attno, g1, b1n, hbuf, hb);
  // ffn1 = relu(h @ w1^T + b1) -> bf16
  gemm_bf16<ushort, 1><<<dim3(kN / 128, 1024 / 128), blk, 0, stream>>>(
      hb, w1b, bb1, f1, kN, 1024, kD);
  // ffn2 -> fp32
  gemm_bf16<float, 0><<<dim3(kN / 128, kD / 128), blk, 0, stream>>>(
      f1, w2b, bb2, f2, kN, kD, 2 * kD);
  // out = LN(h + ffn2)
  ln_kernel<<<dim3(kN / 4), blk, 0, stream>>>(hbuf, f2, g2, b2n, out, nullptr);
}

// Round 4
// 214.304 us; speedup vs baseline: 4.7252x; 1.2310x over previous
//
#include <hip/hip_runtime.h>
#include <cstdint>
#include <cstddef>

static constexpr int kT  = 2048;
static constexpr int kD  = 512;
static constexpr int kB  = 2;
static constexpr int kN  = kB * kT;   // 4096 rows

using short8 = __attribute__((ext_vector_type(8))) short;
using f32x4  = __attribute__((ext_vector_type(4))) float;
typedef unsigned short ushort;

__device__ inline ushort f2bf(float f) {
  uint32_t u = __builtin_bit_cast(uint32_t, f);
  uint32_t r = (u + 0x7FFFu + ((u >> 16) & 1u)) >> 16;
  return (ushort)r;
}

#define GLOAD_LDS16(g, l)                                         \
  __builtin_amdgcn_global_load_lds(                               \
      (const __attribute__((address_space(1))) void*)(g),         \
      (__attribute__((address_space(3))) void*)(l), 16, 0, 0)

// ---------------------------------------------------------------- casts
__global__ __launch_bounds__(256) void cast_kernel(
    const float* __restrict__ in, ushort* __restrict__ out, int n4)
{
  for (int t = blockIdx.x * 256 + threadIdx.x; t < n4; t += gridDim.x * 256) {
    float4 v = *reinterpret_cast<const float4*>(&in[(size_t)t * 4]);
    ushort o[4] = {f2bf(v.x), f2bf(v.y), f2bf(v.z), f2bf(v.w)};
    *reinterpret_cast<uint2*>(&out[(size_t)t * 4]) =
        *reinterpret_cast<uint2*>(o);
  }
}

// W_cat[o][tap*512 + i] = conv_w[o][i][tap]
__global__ __launch_bounds__(256) void convw_kernel(
    const float* __restrict__ cw, ushort* __restrict__ wcat)
{
  for (int t = blockIdx.x * 256 + threadIdx.x; t < kD * kD;
       t += gridDim.x * 256) {
    int o = t >> 9, i = t & 511;
    const float* src = &cw[(size_t)(o * kD + i) * 3];
    ushort* dst = &wcat[(size_t)o * (3 * kD) + i];
#pragma unroll
    for (int tap = 0; tap < 3; ++tap) dst[tap * kD] = f2bf(src[tap]);
  }
}

// A_cat[m][tap*512 + i8*8 ..+8] = xb[m+tap-1][i8*8..] (0 at batch edges)
__global__ __launch_bounds__(256) void acat_kernel(
    const ushort* __restrict__ xb, ushort* __restrict__ acat)
{
  const int total = kN * 3 * 64;
  for (int t = blockIdx.x * 256 + threadIdx.x; t < total;
       t += gridDim.x * 256) {
    int m = t / 192, r = t - m * 192;
    int tap = r >> 6, i8 = r & 63;
    int tib = (m & (kT - 1)) + tap - 1;
    uint4 v = {0u, 0u, 0u, 0u};
    if (tib >= 0 && tib < kT)
      v = *reinterpret_cast<const uint4*>(&xb[(size_t)(m + tap - 1) * kD + i8 * 8]);
    *reinterpret_cast<uint4*>(&acat[(size_t)m * (3 * kD) + tap * kD + i8 * 8]) = v;
  }
}

// ---------------------------------------------------------------- MFMA GEMM
// C[M,Nn] = A[M,K] @ W[Nn,K]^T + bias. A,W bf16 row-major; OutT float/ushort.
// 64x64 tile, BK=64, 256 threads = 4 waves (2x2), wave does 32x32.
// Double-buffered LDS, counted vmcnt, XOR-swizzled staging (T2+T3).
template <typename OutT, int RELU>
__global__ __launch_bounds__(256) void gemm_bf16(
    const ushort* __restrict__ A, const ushort* __restrict__ W,
    const float* __restrict__ bias, OutT* __restrict__ C,
    int M, int Nn, int K)
{
  __shared__ __align__(16) ushort As[2][64 * 64];
  __shared__ __align__(16) ushort Bs[2][64 * 64];
  const int tid = threadIdx.x;
  const int lane = tid & 63, w = tid >> 6;
  const int wr = w >> 1, wc = w & 1;
  const int m0 = blockIdx.x * 64, n0 = blockIdx.y * 64;
  const int fr = lane & 15, g = lane >> 4;

  f32x4 acc[2][2];
#pragma unroll
  for (int i = 0; i < 2; ++i)
#pragma unroll
    for (int j = 0; j < 2; ++j) acc[i][j] = {0.f, 0.f, 0.f, 0.f};

  // staging: 2 issues x 256 threads x 16B = 8KB per matrix per K-step.
  // LDS layout linear [row][chunk], global source chunk = lds_chunk ^ (row&7).
  const int u0 = tid, u1 = tid + 256;
  const int r0s = u0 >> 3, c0s = (u0 & 7) ^ (r0s & 7);
  const int r1s = u1 >> 3, c1s = (u1 & 7) ^ (r1s & 7);
  const ushort* gA0 = A + (size_t)(m0 + r0s) * K + c0s * 8;
  const ushort* gA1 = A + (size_t)(m0 + r1s) * K + c1s * 8;
  const ushort* gB0 = W + (size_t)(n0 + r0s) * K + c0s * 8;
  const ushort* gB1 = W + (size_t)(n0 + r1s) * K + c1s * 8;
  const int ld0 = w * 512;          // ushort offset, wave-uniform
  const int ld1 = 2048 + w * 512;

  auto stage = [&](int buf, int k0) {
    GLOAD_LDS16(gA0 + k0, &As[buf][ld0]);
    GLOAD_LDS16(gA1 + k0, &As[buf][ld1]);
    GLOAD_LDS16(gB0 + k0, &Bs[buf][ld0]);
    GLOAD_LDS16(gB1 + k0, &Bs[buf][ld1]);
  };

  const int nt = K >> 6;
  stage(0, 0);
  int cur = 0;
  for (int t = 0; t < nt; ++t) {
    if (t + 1 < nt) {
      stage(cur ^ 1, (t + 1) << 6);
      asm volatile("s_waitcnt vmcnt(4)" ::: "memory");
    } else {
      asm volatile("s_waitcnt vmcnt(0)" ::: "memory");
    }
    __builtin_amdgcn_s_barrier();
    __builtin_amdgcn_sched_barrier(0);

    short8 a[2][2], b[2][2];
#pragma unroll
    for (int m = 0; m < 2; ++m)
#pragma unroll
      for (int kc = 0; kc < 2; ++kc) {
        int r = wr * 32 + m * 16 + fr;
        a[m][kc] = *reinterpret_cast<const short8*>(
            &As[cur][r * 64 + (((kc * 4 + g) ^ (r & 7)) * 8)]);
      }
#pragma unroll
    for (int n = 0; n < 2; ++n)
#pragma unroll
      for (int kc = 0; kc < 2; ++kc) {
        int r = wc * 32 + n * 16 + fr;
        b[n][kc] = *reinterpret_cast<const short8*>(
            &Bs[cur][r * 64 + (((kc * 4 + g) ^ (r & 7)) * 8)]);
      }
#pragma unroll
    for (int m = 0; m < 2; ++m)
#pragma unroll
      for (int n = 0; n < 2; ++n)
#pragma unroll
        for (int kc = 0; kc < 2; ++kc)
          acc[m][n] = __builtin_amdgcn_mfma_f32_16x16x32_bf16(
              a[m][kc], b[n][kc], acc[m][n], 0, 0, 0);

    __builtin_amdgcn_sched_barrier(0);
    __builtin_amdgcn_s_barrier();
    cur ^= 1;
  }

  float bv[2];
#pragma unroll
  for (int n = 0; n < 2; ++n) bv[n] = bias[n0 + wc * 32 + n * 16 + fr];
#pragma unroll
  for (int m = 0; m < 2; ++m) {
#pragma unroll
    for (int j = 0; j < 4; ++j) {
      int row = m0 + wr * 32 + m * 16 + g * 4 + j;
#pragma unroll
      for (int n = 0; n < 2; ++n) {
        int col = n0 + wc * 32 + n * 16 + fr;
        float v = acc[m][n][j] + bv[n];
        if (RELU) v = fmaxf(v, 0.f);
        if constexpr (sizeof(OutT) == 2)
          C[(size_t)row * Nn + col] = (OutT)f2bf(v);
        else
          C[(size_t)row * Nn + col] = (OutT)v;
      }
    }
  }
}

// ---------------------------------------------------------------- banded MFMA attention
// QK: [N,1024] bf16 (q | k), V: [N,512] bf16, Ctx: [N,512] bf16.
__global__ __launch_bounds__(256) void attn_mfma(
    const ushort* __restrict__ QK, const ushort* __restrict__ V,
    ushort* __restrict__ Ctx)
{
  constexpr int PAD = 72;
  __shared__ __align__(16) ushort Ks[64 * 64];      // XOR-swizzled 16B units
  __shared__ __align__(16) ushort Vt[64][PAD];      // transposed V: [d][j]
  __shared__ __align__(16) ushort Pl[4][16][PAD];   // per-wave P
  const int tid = threadIdx.x;
  const int lane = tid & 63, w = tid >> 6;
  const int l15 = lane & 15, g = lane >> 4;
  const int bh = blockIdx.y;
  const int b = bh >> 3, h = bh & 7;
  const int r0 = blockIdx.x * 64;
  const int rowbase = b * kT;
  const int qrow0 = r0 + w * 16;
  const int t_lo = max(r0 - 256, 0);
  const int t_last = min(r0 + 256, kT - 64);
  const int ntiles = ((t_last - t_lo) >> 6) + 1;

  short8 qf[2];
  {
    const size_t qb = (size_t)(rowbase + qrow0 + l15) * 1024 + h * 64 + g * 8;
    qf[0] = *reinterpret_cast<const short8*>(&QK[qb]);
    qf[1] = *reinterpret_cast<const short8*>(&QK[qb + 32]);
  }

  f32x4 acc[4];
#pragma unroll
  for (int d = 0; d < 4; ++d) acc[d] = {0.f, 0.f, 0.f, 0.f};
  float mrun[4] = {-1e30f, -1e30f, -1e30f, -1e30f};
  float lrun[4] = {0.f, 0.f, 0.f, 0.f};

  for (int tt = 0; tt < ntiles; ++tt) {
    const int j0 = t_lo + tt * 64;

#pragma unroll
    for (int c = 0; c < 2; ++c) {
      int u = c * 256 + tid;
      int row = u >> 3;
      int col8 = (u & 7) ^ (row & 7);
      const ushort* src =
          &QK[(size_t)(rowbase + j0 + row) * 1024 + 512 + h * 64 + col8 * 8];
      GLOAD_LDS16(src, &Ks[(c * 256 + w * 64) * 8]);
    }
#pragma unroll
    for (int i = 0; i < 2; ++i) {
      int dg = w + 4 * i;
      uint4 vv = *reinterpret_cast<const uint4*>(
          &V[(size_t)(rowbase + j0 + lane) * 512 + h * 64 + dg * 8]);
      ushort tmp[8];
      *reinterpret_cast<uint4*>(tmp) = vv;
#pragma unroll
      for (int e = 0; e < 8; ++e) Vt[dg * 8 + e][lane] = tmp[e];
    }
    __syncthreads();

    f32x4 s[4];
#pragma unroll
    for (int n = 0; n < 4; ++n) {
      f32x4 z = {0.f, 0.f, 0.f, 0.f};
#pragma unroll
      for (int kc = 0; kc < 2; ++kc) {
        int row = n * 16 + l15;
        int unit = row * 8 + ((kc * 4 + g) ^ (row & 7));
        short8 kb = *reinterpret_cast<const short8*>(&Ks[unit * 8]);
        z = __builtin_amdgcn_mfma_f32_16x16x32_bf16(qf[kc], kb, z, 0, 0, 0);
      }
      s[n] = z;
    }
#pragma unroll
    for (int n = 0; n < 4; ++n)
#pragma unroll
      for (int j = 0; j < 4; ++j) {
        int col = j0 + n * 16 + l15;
        int qr = qrow0 + g * 4 + j;
        int dlt = col - qr;
        float v = s[n][j] * 0.125f;
        s[n][j] = (dlt > 256 || dlt < -256) ? -1e30f : v;
      }
    float pn[4][4];
    float sold[4];
#pragma unroll
    for (int j = 0; j < 4; ++j) {
      float mx = fmaxf(fmaxf(s[0][j], s[1][j]), fmaxf(s[2][j], s[3][j]));
      mx = fmaxf(mx, __shfl_xor(mx, 1));
      mx = fmaxf(mx, __shfl_xor(mx, 2));
      mx = fmaxf(mx, __shfl_xor(mx, 4));
      mx = fmaxf(mx, __shfl_xor(mx, 8));
      float mnew = fmaxf(mrun[j], mx);
      float sc = __expf(mrun[j] - mnew);
      mrun[j] = mnew;
      sold[j] = sc;
      float rs = 0.f;
#pragma unroll
      for (int n = 0; n < 4; ++n) {
        float p = __expf(s[n][j] - mnew);
        pn[n][j] = p;
        rs += p;
      }
      rs += __shfl_xor(rs, 1);
      rs += __shfl_xor(rs, 2);
      rs += __shfl_xor(rs, 4);
      rs += __shfl_xor(rs, 8);
      lrun[j] = lrun[j] * sc + rs;
    }
#pragma unroll
    for (int d = 0; d < 4; ++d)
#pragma unroll
      for (int j = 0; j < 4; ++j) acc[d][j] *= sold[j];
#pragma unroll
    for (int n = 0; n < 4; ++n)
#pragma unroll
      for (int j = 0; j < 4; ++j)
        Pl[w][g * 4 + j][n * 16 + l15] = f2bf(pn[n][j]);
    asm volatile("s_waitcnt lgkmcnt(0)" ::: "memory");
    __builtin_amdgcn_sched_barrier(0);

    short8 pa[2];
    pa[0] = *reinterpret_cast<const short8*>(&Pl[w][l15][g * 8]);
    pa[1] = *reinterpret_cast<const short8*>(&Pl[w][l15][32 + g * 8]);
#pragma unroll
    for (int d = 0; d < 4; ++d) {
#pragma unroll
      for (int kc = 0; kc < 2; ++kc) {
        short8 vb = *reinterpret_cast<const short8*>(
            &Vt[d * 16 + l15][kc * 32 + g * 8]);
        acc[d] = __builtin_amdgcn_mfma_f32_16x16x32_bf16(pa[kc], vb, acc[d], 0, 0, 0);
      }
    }
    __syncthreads();
  }

  float inv[4];
#pragma unroll
  for (int j = 0; j < 4; ++j) inv[j] = 1.f / lrun[j];
#pragma unroll
  for (int d = 0; d < 4; ++d)
#pragma unroll
    for (int j = 0; j < 4; ++j) {
      float v = acc[d][j] * inv[j];
      Ctx[(size_t)(rowbase + qrow0 + g * 4 + j) * 512 + h * 64 + d * 16 + l15] =
          f2bf(v);
    }
}

// ---------------------------------------------------------------- residual + LayerNorm
__global__ __launch_bounds__(256) void ln_kernel(
    const float* __restrict__ A, const float* __restrict__ Bq,
    const float* __restrict__ G, const float* __restrict__ Bt,
    float* __restrict__ Out, ushort* __restrict__ OutB)
{
  const int lane = threadIdx.x & 63;
  const int wv = threadIdx.x >> 6;
  const int row = blockIdx.x * 4 + wv;
  const size_t base = (size_t)row * kD + lane * 8;

  float4 a0 = *reinterpret_cast<const float4*>(&A[base]);
  float4 a1 = *reinterpret_cast<const float4*>(&A[base + 4]);
  float4 b0 = *reinterpret_cast<const float4*>(&Bq[base]);
  float4 b1 = *reinterpret_cast<const float4*>(&Bq[base + 4]);
  float x[8] = {a0.x + b0.x, a0.y + b0.y, a0.z + b0.z, a0.w + b0.w,
                a1.x + b1.x, a1.y + b1.y, a1.z + b1.z, a1.w + b1.w};
  float s = 0.f, ss = 0.f;
#pragma unroll
  for (int i = 0; i < 8; ++i) { s += x[i]; ss += x[i] * x[i]; }
#pragma unroll
  for (int o = 1; o < 64; o <<= 1) {
    s += __shfl_xor(s, o, 64);
    ss += __shfl_xor(ss, o, 64);
  }
  const float mean = s * (1.f / kD);
  const float var = ss * (1.f / kD) - mean * mean;
  const float rs = rsqrtf(var + 1e-5f);

  const int c = lane * 8;
  float4 g0 = *reinterpret_cast<const float4*>(&G[c]);
  float4 g1 = *reinterpret_cast<const float4*>(&G[c + 4]);
  float4 t0 = *reinterpret_cast<const float4*>(&Bt[c]);
  float4 t1 = *reinterpret_cast<const float4*>(&Bt[c + 4]);
  float y[8];
  y[0] = (x[0] - mean) * rs * g0.x + t0.x;
  y[1] = (x[1] - mean) * rs * g0.y + t0.y;
  y[2] = (x[2] - mean) * rs * g0.z + t0.z;
  y[3] = (x[3] - mean) * rs * g0.w + t0.w;
  y[4] = (x[4] - mean) * rs * g1.x + t1.x;
  y[5] = (x[5] - mean) * rs * g1.y + t1.y;
  y[6] = (x[6] - mean) * rs * g1.z + t1.z;
  y[7] = (x[7] - mean) * rs * g1.w + t1.w;
  *reinterpret_cast<float4*>(&Out[base]) = {y[0], y[1], y[2], y[3]};
  *reinterpret_cast<float4*>(&Out[base + 4]) = {y[4], y[5], y[6], y[7]};
  if (OutB) {
    ushort ob[8];
#pragma unroll
    for (int i = 0; i < 8; ++i) ob[i] = f2bf(y[i]);
    *reinterpret_cast<uint4*>(&OutB[base]) = *reinterpret_cast<uint4*>(ob);
  }
}

// ---------------------------------------------------------------- launch
extern "C" void kernel_launch(void* const* d_in, const int* in_sizes, int n_in,
                              void* d_out, int out_size, void* d_ws, size_t ws_size,
                              hipStream_t stream)
{
  const float* x   = (const float*)d_in[0];
  const float* cw  = (const float*)d_in[2];
  const float* cb  = (const float*)d_in[3];
  const float* ipw = (const float*)d_in[4];
  const float* ipb = (const float*)d_in[5];
  const float* opw = (const float*)d_in[6];
  const float* opb = (const float*)d_in[7];
  const float* g1  = (const float*)d_in[8];
  const float* b1n = (const float*)d_in[9];
  const float* w1  = (const float*)d_in[10];
  const float* bb1 = (const float*)d_in[11];
  const float* w2  = (const float*)d_in[12];
  const float* bb2 = (const float*)d_in[13];
  const float* g2  = (const float*)d_in[14];
  const float* b2n = (const float*)d_in[15];
  float* out = (float*)d_out;

  char* p = (char*)d_ws;
  auto take = [&](size_t bytes) {
    char* q = p; p += (bytes + 255) & ~size_t(255); return q;
  };
  ushort* xb    = (ushort*)take((size_t)kN * kD * 2);
  char*  acat_r =          take((size_t)kN * 3 * kD * 2);   // 12MB region
  ushort* acat  = (ushort*)acat_r;
  ushort* wcat  = (ushort*)take((size_t)kD * 3 * kD * 2);
  ushort* ipwb  = (ushort*)take((size_t)3 * kD * kD * 2);
  ushort* opwb  = (ushort*)take((size_t)kD * kD * 2);
  ushort* w1b   = (ushort*)take((size_t)2 * kD * kD * 2);
  ushort* w2b   = (ushort*)take((size_t)2 * kD * kD * 2);
  ushort* convo = (ushort*)take((size_t)kN * kD * 2);
  char*  qk_r   =          take((size_t)kN * 2 * kD * 2);   // 8MB, bf16 q|k
  ushort* qkb   = (ushort*)qk_r;
  ushort* vbb   = (ushort*)take((size_t)kN * kD * 2);
  ushort* ctx   = (ushort*)take((size_t)kN * kD * 2);
  float* hbuf   = (float*)take((size_t)kN * kD * 4);
  ushort* hb    = (ushort*)take((size_t)kN * kD * 2);
  float* attno  = (float*)acat_r;    // acat dead after conv GEMM
  ushort* f1    = (ushort*)qk_r;     // qkb dead after attention
  float* f2     = (float*)acat_r;    // attno dead after LN1

  dim3 blk(256);
  cast_kernel<<<dim3(1024), blk, 0, stream>>>(x, xb, kN * kD / 4);
  cast_kernel<<<dim3(512), blk, 0, stream>>>(ipw, ipwb, 3 * kD * kD / 4);
  cast_kernel<<<dim3(256), blk, 0, stream>>>(opw, opwb, kD * kD / 4);
  cast_kernel<<<dim3(512), blk, 0, stream>>>(w1, w1b, 2 * kD * kD / 4);
  cast_kernel<<<dim3(512), blk, 0, stream>>>(w2, w2b, 2 * kD * kD / 4);
  convw_kernel<<<dim3(1024), blk, 0, stream>>>(cw, wcat);
  acat_kernel<<<dim3(1024), blk, 0, stream>>>(xb, acat);

  // conv as GEMM -> bf16
  gemm_bf16<ushort, 0><<<dim3(kN / 64, kD / 64), blk, 0, stream>>>(
      acat, wcat, cb, convo, kN, kD, 3 * kD);
  // q,k projection -> bf16
  gemm_bf16<ushort, 0><<<dim3(kN / 64, 1024 / 64), blk, 0, stream>>>(
      xb, ipwb, ipb, qkb, kN, 1024, kD);
  // v projection -> bf16
  gemm_bf16<ushort, 0><<<dim3(kN / 64, kD / 64), blk, 0, stream>>>(
      convo, ipwb + (size_t)1024 * kD, ipb + 1024, vbb, kN, kD, kD);
  // banded MFMA attention -> bf16 ctx
  attn_mfma<<<dim3(kT / 64, kB * 8), blk, 0, stream>>>(qkb, vbb, ctx);
  // out projection -> fp32
  gemm_bf16<float, 0><<<dim3(kN / 64, kD / 64), blk, 0, stream>>>(
      ctx, opwb, opb, attno, kN, kD, kD);
  // h = LN(x + attn_out)
  ln_kernel<<<dim3(kN / 4), blk, 0, stream>>>(x, attno, g1, b1n, hbuf, hb);
  // ffn1 = relu(h @ w1^T + b1) -> bf16
  gemm_bf16<ushort, 1><<<dim3(kN / 64, 1024 / 64), blk, 0, stream>>>(
      hb, w1b, bb1, f1, kN, 1024, kD);
  // ffn2 -> fp32
  gemm_bf16<float, 0><<<dim3(kN / 64, kD / 64), blk, 0, stream>>>(
      f1, w2b, bb2, f2, kN, kD, 2 * kD);
  // out = LN(h + ffn2)
  ln_kernel<<<dim3(kN / 4), blk, 0, stream>>>(hbuf, f2, g2, b2n, out, nullptr);
}

// Round 5
// 210.899 us; speedup vs baseline: 4.8015x; 1.0161x over previous
//
#include <hip/hip_runtime.h>
#include <cstdint>
#include <cstddef>

static constexpr int kT  = 2048;
static constexpr int kD  = 512;
static constexpr int kB  = 2;
static constexpr int kN  = kB * kT;   // 4096 rows

using short8 = __attribute__((ext_vector_type(8))) short;
using f32x4  = __attribute__((ext_vector_type(4))) float;
typedef unsigned short ushort;

__device__ inline ushort f2bf(float f) {
  uint32_t u = __builtin_bit_cast(uint32_t, f);
  uint32_t r = (u + 0x7FFFu + ((u >> 16) & 1u)) >> 16;
  return (ushort)r;
}

#define GLOAD_LDS16(g, l)                                         \
  __builtin_amdgcn_global_load_lds(                               \
      (const __attribute__((address_space(1))) void*)(g),         \
      (__attribute__((address_space(3))) void*)(l), 16, 0, 0)

// ---------------------------------------------------------------- fused prep
// One kernel: x->bf16, 4 weight casts, conv-weight transform, im2col acat.
__global__ __launch_bounds__(256) void prep_kernel(
    const float* __restrict__ x,   const float* __restrict__ ipw,
    const float* __restrict__ opw, const float* __restrict__ w1,
    const float* __restrict__ w2,  const float* __restrict__ cw,
    ushort* __restrict__ xb,   ushort* __restrict__ ipwb,
    ushort* __restrict__ opwb, ushort* __restrict__ w1b,
    ushort* __restrict__ w2b,  ushort* __restrict__ wcat,
    ushort* __restrict__ acat)
{
  constexpr int C0 = 524288;            // xb cast (float4 units)
  constexpr int C1 = C0 + 196608;       // ipw
  constexpr int C2 = C1 + 65536;        // opw
  constexpr int C3 = C2 + 131072;       // w1
  constexpr int C4 = C3 + 131072;       // w2
  constexpr int C5 = C4 + 262144;       // convw transform (o,i units)
  constexpr int C6 = C5 + 786432;       // acat (m,tap,i8 units)

  auto cast4 = [](const float* in, ushort* out, int u) {
    float4 v = *reinterpret_cast<const float4*>(&in[(size_t)u * 4]);
    ushort o[4] = {f2bf(v.x), f2bf(v.y), f2bf(v.z), f2bf(v.w)};
    *reinterpret_cast<uint2*>(&out[(size_t)u * 4]) =
        *reinterpret_cast<uint2*>(o);
  };

  for (int u = blockIdx.x * 256 + threadIdx.x; u < C6; u += gridDim.x * 256) {
    if (u < C0) {
      cast4(x, xb, u);
    } else if (u < C1) {
      cast4(ipw, ipwb, u - C0);
    } else if (u < C2) {
      cast4(opw, opwb, u - C1);
    } else if (u < C3) {
      cast4(w1, w1b, u - C2);
    } else if (u < C4) {
      cast4(w2, w2b, u - C3);
    } else if (u < C5) {
      int t = u - C4;
      int o = t >> 9, i = t & 511;
      const float* src = &cw[(size_t)(o * kD + i) * 3];
      ushort* dst = &wcat[(size_t)o * (3 * kD) + i];
#pragma unroll
      for (int tap = 0; tap < 3; ++tap) dst[tap * kD] = f2bf(src[tap]);
    } else {
      int t = u - C5;
      int m = t / 192, r = t - m * 192;
      int tap = r >> 6, i8 = r & 63;
      int tib = (m & (kT - 1)) + tap - 1;
      ushort ob[8] = {0, 0, 0, 0, 0, 0, 0, 0};
      if (tib >= 0 && tib < kT) {
        const float* src = &x[(size_t)(m + tap - 1) * kD + i8 * 8];
        float4 v0 = *reinterpret_cast<const float4*>(src);
        float4 v1 = *reinterpret_cast<const float4*>(src + 4);
        ob[0] = f2bf(v0.x); ob[1] = f2bf(v0.y); ob[2] = f2bf(v0.z);
        ob[3] = f2bf(v0.w); ob[4] = f2bf(v1.x); ob[5] = f2bf(v1.y);
        ob[6] = f2bf(v1.z); ob[7] = f2bf(v1.w);
      }
      *reinterpret_cast<uint4*>(
          &acat[(size_t)m * (3 * kD) + tap * kD + i8 * 8]) =
          *reinterpret_cast<uint4*>(ob);
    }
  }
}

// ---------------------------------------------------------------- MFMA GEMM
// C[M,Nn] = A[M,K] @ W[Nn,K]^T + bias. 64x64 tile, BK=64, 4 waves (2x2).
// 3-buffer LDS ring, 2-tile-deep prefetch, counted vmcnt, XOR swizzle.
template <typename OutT, int RELU>
__global__ __launch_bounds__(256) void gemm_bf16(
    const ushort* __restrict__ A, const ushort* __restrict__ W,
    const float* __restrict__ bias, OutT* __restrict__ C,
    int M, int Nn, int K)
{
  __shared__ __align__(16) ushort As[3][64 * 64];
  __shared__ __align__(16) ushort Bs[3][64 * 64];
  const int tid = threadIdx.x;
  const int lane = tid & 63, w = tid >> 6;
  const int wr = w >> 1, wc = w & 1;
  const int m0 = blockIdx.x * 64, n0 = blockIdx.y * 64;
  const int fr = lane & 15, g = lane >> 4;

  f32x4 acc[2][2];
#pragma unroll
  for (int i = 0; i < 2; ++i)
#pragma unroll
    for (int j = 0; j < 2; ++j) acc[i][j] = {0.f, 0.f, 0.f, 0.f};

  // staging: linear LDS dest, global source chunk = lds_chunk ^ (row&7).
  const int u0 = tid, u1 = tid + 256;
  const int r0s = u0 >> 3, c0s = (u0 & 7) ^ (r0s & 7);
  const int r1s = u1 >> 3, c1s = (u1 & 7) ^ (r1s & 7);
  const ushort* gA0 = A + (size_t)(m0 + r0s) * K + c0s * 8;
  const ushort* gA1 = A + (size_t)(m0 + r1s) * K + c1s * 8;
  const ushort* gB0 = W + (size_t)(n0 + r0s) * K + c0s * 8;
  const ushort* gB1 = W + (size_t)(n0 + r1s) * K + c1s * 8;
  const int ld0 = w * 512;          // ushort offset, wave-uniform
  const int ld1 = 2048 + w * 512;

  auto stage = [&](int buf, int k0) {
    GLOAD_LDS16(gA0 + k0, &As[buf][ld0]);
    GLOAD_LDS16(gA1 + k0, &As[buf][ld1]);
    GLOAD_LDS16(gB0 + k0, &Bs[buf][ld0]);
    GLOAD_LDS16(gB1 + k0, &Bs[buf][ld1]);
  };

  const int nt = K >> 6;            // K >= 512 so nt >= 8
  stage(0, 0);
  stage(1, 64);
  int cur = 0, b2 = 2;
  for (int t = 0; t < nt; ++t) {
    if (t + 2 < nt) {
      stage(b2, (t + 2) << 6);
      asm volatile("s_waitcnt vmcnt(8)" ::: "memory");
    } else if (t + 1 < nt) {
      asm volatile("s_waitcnt vmcnt(4)" ::: "memory");
    } else {
      asm volatile("s_waitcnt vmcnt(0)" ::: "memory");
    }
    __builtin_amdgcn_s_barrier();
    __builtin_amdgcn_sched_barrier(0);

    short8 a[2][2], b[2][2];
#pragma unroll
    for (int m = 0; m < 2; ++m)
#pragma unroll
      for (int kc = 0; kc < 2; ++kc) {
        int r = wr * 32 + m * 16 + fr;
        a[m][kc] = *reinterpret_cast<const short8*>(
            &As[cur][r * 64 + (((kc * 4 + g) ^ (r & 7)) * 8)]);
      }
#pragma unroll
    for (int n = 0; n < 2; ++n)
#pragma unroll
      for (int kc = 0; kc < 2; ++kc) {
        int r = wc * 32 + n * 16 + fr;
        b[n][kc] = *reinterpret_cast<const short8*>(
            &Bs[cur][r * 64 + (((kc * 4 + g) ^ (r & 7)) * 8)]);
      }
#pragma unroll
    for (int m = 0; m < 2; ++m)
#pragma unroll
      for (int n = 0; n < 2; ++n)
#pragma unroll
        for (int kc = 0; kc < 2; ++kc)
          acc[m][n] = __builtin_amdgcn_mfma_f32_16x16x32_bf16(
              a[m][kc], b[n][kc], acc[m][n], 0, 0, 0);

    __builtin_amdgcn_sched_barrier(0);
    __builtin_amdgcn_s_barrier();
    cur = cur == 2 ? 0 : cur + 1;
    b2 = b2 == 2 ? 0 : b2 + 1;
  }

  float bv[2];
#pragma unroll
  for (int n = 0; n < 2; ++n) bv[n] = bias[n0 + wc * 32 + n * 16 + fr];
#pragma unroll
  for (int m = 0; m < 2; ++m) {
#pragma unroll
    for (int j = 0; j < 4; ++j) {
      int row = m0 + wr * 32 + m * 16 + g * 4 + j;
#pragma unroll
      for (int n = 0; n < 2; ++n) {
        int col = n0 + wc * 32 + n * 16 + fr;
        float v = acc[m][n][j] + bv[n];
        if (RELU) v = fmaxf(v, 0.f);
        if constexpr (sizeof(OutT) == 2)
          C[(size_t)row * Nn + col] = (OutT)f2bf(v);
        else
          C[(size_t)row * Nn + col] = (OutT)v;
      }
    }
  }
}

// ---------------------------------------------------------------- banded MFMA attention
// QK: [N,1024] bf16 (q | k), V: [N,512] bf16, Ctx: [N,512] bf16.
__global__ __launch_bounds__(256) void attn_mfma(
    const ushort* __restrict__ QK, const ushort* __restrict__ V,
    ushort* __restrict__ Ctx)
{
  constexpr int PAD = 72;
  __shared__ __align__(16) ushort Ks[64 * 64];      // XOR-swizzled 16B units
  __shared__ __align__(16) ushort Vt[64][PAD];      // transposed V: [d][j]
  __shared__ __align__(16) ushort Pl[4][16][PAD];   // per-wave P
  const int tid = threadIdx.x;
  const int lane = tid & 63, w = tid >> 6;
  const int l15 = lane & 15, g = lane >> 4;
  const int bh = blockIdx.y;
  const int b = bh >> 3, h = bh & 7;
  const int r0 = blockIdx.x * 64;
  const int rowbase = b * kT;
  const int qrow0 = r0 + w * 16;
  const int t_lo = max(r0 - 256, 0);
  const int t_last = min(r0 + 256, kT - 64);
  const int ntiles = ((t_last - t_lo) >> 6) + 1;

  short8 qf[2];
  {
    const size_t qb = (size_t)(rowbase + qrow0 + l15) * 1024 + h * 64 + g * 8;
    qf[0] = *reinterpret_cast<const short8*>(&QK[qb]);
    qf[1] = *reinterpret_cast<const short8*>(&QK[qb + 32]);
  }

  f32x4 acc[4];
#pragma unroll
  for (int d = 0; d < 4; ++d) acc[d] = {0.f, 0.f, 0.f, 0.f};
  float mrun[4] = {-1e30f, -1e30f, -1e30f, -1e30f};
  float lrun[4] = {0.f, 0.f, 0.f, 0.f};

  for (int tt = 0; tt < ntiles; ++tt) {
    const int j0 = t_lo + tt * 64;

#pragma unroll
    for (int c = 0; c < 2; ++c) {
      int u = c * 256 + tid;
      int row = u >> 3;
      int col8 = (u & 7) ^ (row & 7);
      const ushort* src =
          &QK[(size_t)(rowbase + j0 + row) * 1024 + 512 + h * 64 + col8 * 8];
      GLOAD_LDS16(src, &Ks[(c * 256 + w * 64) * 8]);
    }
#pragma unroll
    for (int i = 0; i < 2; ++i) {
      int dg = w + 4 * i;
      uint4 vv = *reinterpret_cast<const uint4*>(
          &V[(size_t)(rowbase + j0 + lane) * 512 + h * 64 + dg * 8]);
      ushort tmp[8];
      *reinterpret_cast<uint4*>(tmp) = vv;
#pragma unroll
      for (int e = 0; e < 8; ++e) Vt[dg * 8 + e][lane] = tmp[e];
    }
    __syncthreads();

    f32x4 s[4];
#pragma unroll
    for (int n = 0; n < 4; ++n) {
      f32x4 z = {0.f, 0.f, 0.f, 0.f};
#pragma unroll
      for (int kc = 0; kc < 2; ++kc) {
        int row = n * 16 + l15;
        int unit = row * 8 + ((kc * 4 + g) ^ (row & 7));
        short8 kb = *reinterpret_cast<const short8*>(&Ks[unit * 8]);
        z = __builtin_amdgcn_mfma_f32_16x16x32_bf16(qf[kc], kb, z, 0, 0, 0);
      }
      s[n] = z;
    }
#pragma unroll
    for (int n = 0; n < 4; ++n)
#pragma unroll
      for (int j = 0; j < 4; ++j) {
        int col = j0 + n * 16 + l15;
        int qr = qrow0 + g * 4 + j;
        int dlt = col - qr;
        float v = s[n][j] * 0.125f;
        s[n][j] = (dlt > 256 || dlt < -256) ? -1e30f : v;
      }
    float pn[4][4];
    float sold[4];
#pragma unroll
    for (int j = 0; j < 4; ++j) {
      float mx = fmaxf(fmaxf(s[0][j], s[1][j]), fmaxf(s[2][j], s[3][j]));
      mx = fmaxf(mx, __shfl_xor(mx, 1));
      mx = fmaxf(mx, __shfl_xor(mx, 2));
      mx = fmaxf(mx, __shfl_xor(mx, 4));
      mx = fmaxf(mx, __shfl_xor(mx, 8));
      float mnew = fmaxf(mrun[j], mx);
      float sc = __expf(mrun[j] - mnew);
      mrun[j] = mnew;
      sold[j] = sc;
      float rs = 0.f;
#pragma unroll
      for (int n = 0; n < 4; ++n) {
        float p = __expf(s[n][j] - mnew);
        pn[n][j] = p;
        rs += p;
      }
      rs += __shfl_xor(rs, 1);
      rs += __shfl_xor(rs, 2);
      rs += __shfl_xor(rs, 4);
      rs += __shfl_xor(rs, 8);
      lrun[j] = lrun[j] * sc + rs;
    }
#pragma unroll
    for (int d = 0; d < 4; ++d)
#pragma unroll
      for (int j = 0; j < 4; ++j) acc[d][j] *= sold[j];
#pragma unroll
    for (int n = 0; n < 4; ++n)
#pragma unroll
      for (int j = 0; j < 4; ++j)
        Pl[w][g * 4 + j][n * 16 + l15] = f2bf(pn[n][j]);
    asm volatile("s_waitcnt lgkmcnt(0)" ::: "memory");
    __builtin_amdgcn_sched_barrier(0);

    short8 pa[2];
    pa[0] = *reinterpret_cast<const short8*>(&Pl[w][l15][g * 8]);
    pa[1] = *reinterpret_cast<const short8*>(&Pl[w][l15][32 + g * 8]);
#pragma unroll
    for (int d = 0; d < 4; ++d) {
#pragma unroll
      for (int kc = 0; kc < 2; ++kc) {
        short8 vb = *reinterpret_cast<const short8*>(
            &Vt[d * 16 + l15][kc * 32 + g * 8]);
        acc[d] = __builtin_amdgcn_mfma_f32_16x16x32_bf16(pa[kc], vb, acc[d], 0, 0, 0);
      }
    }
    __syncthreads();
  }

  float inv[4];
#pragma unroll
  for (int j = 0; j < 4; ++j) inv[j] = 1.f / lrun[j];
#pragma unroll
  for (int d = 0; d < 4; ++d)
#pragma unroll
    for (int j = 0; j < 4; ++j) {
      float v = acc[d][j] * inv[j];
      Ctx[(size_t)(rowbase + qrow0 + g * 4 + j) * 512 + h * 64 + d * 16 + l15] =
          f2bf(v);
    }
}

// ---------------------------------------------------------------- residual + LayerNorm
__global__ __launch_bounds__(256) void ln_kernel(
    const float* __restrict__ A, const float* __restrict__ Bq,
    const float* __restrict__ G, const float* __restrict__ Bt,
    float* __restrict__ Out, ushort* __restrict__ OutB)
{
  const int lane = threadIdx.x & 63;
  const int wv = threadIdx.x >> 6;
  const int row = blockIdx.x * 4 + wv;
  const size_t base = (size_t)row * kD + lane * 8;

  float4 a0 = *reinterpret_cast<const float4*>(&A[base]);
  float4 a1 = *reinterpret_cast<const float4*>(&A[base + 4]);
  float4 b0 = *reinterpret_cast<const float4*>(&Bq[base]);
  float4 b1 = *reinterpret_cast<const float4*>(&Bq[base + 4]);
  float x[8] = {a0.x + b0.x, a0.y + b0.y, a0.z + b0.z, a0.w + b0.w,
                a1.x + b1.x, a1.y + b1.y, a1.z + b1.z, a1.w + b1.w};
  float s = 0.f, ss = 0.f;
#pragma unroll
  for (int i = 0; i < 8; ++i) { s += x[i]; ss += x[i] * x[i]; }
#pragma unroll
  for (int o = 1; o < 64; o <<= 1) {
    s += __shfl_xor(s, o, 64);
    ss += __shfl_xor(ss, o, 64);
  }
  const float mean = s * (1.f / kD);
  const float var = ss * (1.f / kD) - mean * mean;
  const float rs = rsqrtf(var + 1e-5f);

  const int c = lane * 8;
  float4 g0 = *reinterpret_cast<const float4*>(&G[c]);
  float4 g1 = *reinterpret_cast<const float4*>(&G[c + 4]);
  float4 t0 = *reinterpret_cast<const float4*>(&Bt[c]);
  float4 t1 = *reinterpret_cast<const float4*>(&Bt[c + 4]);
  float y[8];
  y[0] = (x[0] - mean) * rs * g0.x + t0.x;
  y[1] = (x[1] - mean) * rs * g0.y + t0.y;
  y[2] = (x[2] - mean) * rs * g0.z + t0.z;
  y[3] = (x[3] - mean) * rs * g0.w + t0.w;
  y[4] = (x[4] - mean) * rs * g1.x + t1.x;
  y[5] = (x[5] - mean) * rs * g1.y + t1.y;
  y[6] = (x[6] - mean) * rs * g1.z + t1.z;
  y[7] = (x[7] - mean) * rs * g1.w + t1.w;
  *reinterpret_cast<float4*>(&Out[base]) = {y[0], y[1], y[2], y[3]};
  *reinterpret_cast<float4*>(&Out[base + 4]) = {y[4], y[5], y[6], y[7]};
  if (OutB) {
    ushort ob[8];
#pragma unroll
    for (int i = 0; i < 8; ++i) ob[i] = f2bf(y[i]);
    *reinterpret_cast<uint4*>(&OutB[base]) = *reinterpret_cast<uint4*>(ob);
  }
}

// ---------------------------------------------------------------- launch
extern "C" void kernel_launch(void* const* d_in, const int* in_sizes, int n_in,
                              void* d_out, int out_size, void* d_ws, size_t ws_size,
                              hipStream_t stream)
{
  const float* x   = (const float*)d_in[0];
  const float* cw  = (const float*)d_in[2];
  const float* cb  = (const float*)d_in[3];
  const float* ipw = (const float*)d_in[4];
  const float* ipb = (const float*)d_in[5];
  const float* opw = (const float*)d_in[6];
  const float* opb = (const float*)d_in[7];
  const float* g1  = (const float*)d_in[8];
  const float* b1n = (const float*)d_in[9];
  const float* w1  = (const float*)d_in[10];
  const float* bb1 = (const float*)d_in[11];
  const float* w2  = (const float*)d_in[12];
  const float* bb2 = (const float*)d_in[13];
  const float* g2  = (const float*)d_in[14];
  const float* b2n = (const float*)d_in[15];
  float* out = (float*)d_out;

  char* p = (char*)d_ws;
  auto take = [&](size_t bytes) {
    char* q = p; p += (bytes + 255) & ~size_t(255); return q;
  };
  ushort* xb    = (ushort*)take((size_t)kN * kD * 2);
  char*  acat_r =          take((size_t)kN * 3 * kD * 2);   // 12MB region
  ushort* acat  = (ushort*)acat_r;
  ushort* wcat  = (ushort*)take((size_t)kD * 3 * kD * 2);
  ushort* ipwb  = (ushort*)take((size_t)3 * kD * kD * 2);
  ushort* opwb  = (ushort*)take((size_t)kD * kD * 2);
  ushort* w1b   = (ushort*)take((size_t)2 * kD * kD * 2);
  ushort* w2b   = (ushort*)take((size_t)2 * kD * kD * 2);
  ushort* convo = (ushort*)take((size_t)kN * kD * 2);
  char*  qk_r   =          take((size_t)kN * 2 * kD * 2);   // 8MB, bf16 q|k
  ushort* qkb   = (ushort*)qk_r;
  ushort* vbb   = (ushort*)take((size_t)kN * kD * 2);
  ushort* ctx   = (ushort*)take((size_t)kN * kD * 2);
  float* hbuf   = (float*)take((size_t)kN * kD * 4);
  ushort* hb    = (ushort*)take((size_t)kN * kD * 2);
  float* attno  = (float*)acat_r;    // acat dead after conv GEMM
  ushort* f1    = (ushort*)qk_r;     // qkb dead after attention
  float* f2     = (float*)acat_r;    // attno dead after LN1

  dim3 blk(256);
  // fused prep: all casts + conv-weight transform + im2col
  prep_kernel<<<dim3(2048), blk, 0, stream>>>(
      x, ipw, opw, w1, w2, cw, xb, ipwb, opwb, w1b, w2b, wcat, acat);

  // conv as GEMM -> bf16
  gemm_bf16<ushort, 0><<<dim3(kN / 64, kD / 64), blk, 0, stream>>>(
      acat, wcat, cb, convo, kN, kD, 3 * kD);
  // q,k projection -> bf16
  gemm_bf16<ushort, 0><<<dim3(kN / 64, 1024 / 64), blk, 0, stream>>>(
      xb, ipwb, ipb, qkb, kN, 1024, kD);
  // v projection -> bf16
  gemm_bf16<ushort, 0><<<dim3(kN / 64, kD / 64), blk, 0, stream>>>(
      convo, ipwb + (size_t)1024 * kD, ipb + 1024, vbb, kN, kD, kD);
  // banded MFMA attention -> bf16 ctx
  attn_mfma<<<dim3(kT / 64, kB * 8), blk, 0, stream>>>(qkb, vbb, ctx);
  // out projection -> fp32
  gemm_bf16<float, 0><<<dim3(kN / 64, kD / 64), blk, 0, stream>>>(
      ctx, opwb, opb, attno, kN, kD, kD);
  // h = LN(x + attn_out)
  ln_kernel<<<dim3(kN / 4), blk, 0, stream>>>(x, attno, g1, b1n, hbuf, hb);
  // ffn1 = relu(h @ w1^T + b1) -> bf16
  gemm_bf16<ushort, 1><<<dim3(kN / 64, 1024 / 64), blk, 0, stream>>>(
      hb, w1b, bb1, f1, kN, 1024, kD);
  // ffn2 -> fp32
  gemm_bf16<float, 0><<<dim3(kN / 64, kD / 64), blk, 0, stream>>>(
      f1, w2b, bb2, f2, kN, kD, 2 * kD);
  // out = LN(h + ffn2)
  ln_kernel<<<dim3(kN / 4), blk, 0, stream>>>(hbuf, f2, g2, b2n, out, nullptr);
}

// Round 6
// 204.495 us; speedup vs baseline: 4.9518x; 1.0313x over previous
//
#include <hip/hip_runtime.h>
#include <cstdint>
#include <cstddef>

static constexpr int kT  = 2048;
static constexpr int kD  = 512;
static constexpr int kB  = 2;
static constexpr int kN  = kB * kT;   // 4096 rows

using short8 = __attribute__((ext_vector_type(8))) short;
using f32x4  = __attribute__((ext_vector_type(4))) float;
typedef unsigned short ushort;

__device__ inline ushort f2bf(float f) {
  uint32_t u = __builtin_bit_cast(uint32_t, f);
  uint32_t r = (u + 0x7FFFu + ((u >> 16) & 1u)) >> 16;
  return (ushort)r;
}

#define GLOAD_LDS16(g, l)                                         \
  __builtin_amdgcn_global_load_lds(                               \
      (const __attribute__((address_space(1))) void*)(g),         \
      (__attribute__((address_space(3))) void*)(l), 16, 0, 0)

// ---------------------------------------------------------------- fused prep
__global__ __launch_bounds__(256) void prep_kernel(
    const float* __restrict__ x,   const float* __restrict__ ipw,
    const float* __restrict__ opw, const float* __restrict__ w1,
    const float* __restrict__ w2,  const float* __restrict__ cw,
    ushort* __restrict__ xb,   ushort* __restrict__ ipwb,
    ushort* __restrict__ opwb, ushort* __restrict__ w1b,
    ushort* __restrict__ w2b,  ushort* __restrict__ wcat,
    ushort* __restrict__ acat)
{
  constexpr int C0 = 524288;            // xb cast (float4 units)
  constexpr int C1 = C0 + 196608;       // ipw
  constexpr int C2 = C1 + 65536;        // opw
  constexpr int C3 = C2 + 131072;       // w1
  constexpr int C4 = C3 + 131072;       // w2
  constexpr int C5 = C4 + 262144;       // convw transform (o,i units)
  constexpr int C6 = C5 + 786432;       // acat (m,tap,i8 units)

  auto cast4 = [](const float* in, ushort* out, int u) {
    float4 v = *reinterpret_cast<const float4*>(&in[(size_t)u * 4]);
    ushort o[4] = {f2bf(v.x), f2bf(v.y), f2bf(v.z), f2bf(v.w)};
    *reinterpret_cast<uint2*>(&out[(size_t)u * 4]) =
        *reinterpret_cast<uint2*>(o);
  };

  for (int u = blockIdx.x * 256 + threadIdx.x; u < C6; u += gridDim.x * 256) {
    if (u < C0) {
      cast4(x, xb, u);
    } else if (u < C1) {
      cast4(ipw, ipwb, u - C0);
    } else if (u < C2) {
      cast4(opw, opwb, u - C1);
    } else if (u < C3) {
      cast4(w1, w1b, u - C2);
    } else if (u < C4) {
      cast4(w2, w2b, u - C3);
    } else if (u < C5) {
      int t = u - C4;
      int o = t >> 9, i = t & 511;
      const float* src = &cw[(size_t)(o * kD + i) * 3];
      ushort* dst = &wcat[(size_t)o * (3 * kD) + i];
#pragma unroll
      for (int tap = 0; tap < 3; ++tap) dst[tap * kD] = f2bf(src[tap]);
    } else {
      int t = u - C5;
      int m = t / 192, r = t - m * 192;
      int tap = r >> 6, i8 = r & 63;
      int tib = (m & (kT - 1)) + tap - 1;
      ushort ob[8] = {0, 0, 0, 0, 0, 0, 0, 0};
      if (tib >= 0 && tib < kT) {
        const float* src = &x[(size_t)(m + tap - 1) * kD + i8 * 8];
        float4 v0 = *reinterpret_cast<const float4*>(src);
        float4 v1 = *reinterpret_cast<const float4*>(src + 4);
        ob[0] = f2bf(v0.x); ob[1] = f2bf(v0.y); ob[2] = f2bf(v0.z);
        ob[3] = f2bf(v0.w); ob[4] = f2bf(v1.x); ob[5] = f2bf(v1.y);
        ob[6] = f2bf(v1.z); ob[7] = f2bf(v1.w);
      }
      *reinterpret_cast<uint4*>(
          &acat[(size_t)m * (3 * kD) + tap * kD + i8 * 8]) =
          *reinterpret_cast<uint4*>(ob);
    }
  }
}

// ---------------------------------------------------------------- MFMA GEMM
// C[M,Nn] = A[M,K] @ W[Nn,K]^T + bias. 64x64 tile, BK=128, 4 waves (2x2),
// wave 32x32, 16 MFMA/step. 2-buffer LDS, 1-ahead prefetch, vmcnt(8).
template <typename OutT, int RELU>
__global__ __launch_bounds__(256) void gemm_bf16(
    const ushort* __restrict__ A, const ushort* __restrict__ W,
    const float* __restrict__ bias, OutT* __restrict__ C,
    int M, int Nn, int K)
{
  __shared__ __align__(16) ushort As[2][64 * 128];
  __shared__ __align__(16) ushort Bs[2][64 * 128];
  const int tid = threadIdx.x;
  const int lane = tid & 63, w = tid >> 6;
  const int wr = w >> 1, wc = w & 1;
  const int m0 = blockIdx.x * 64, n0 = blockIdx.y * 64;
  const int fr = lane & 15, g = lane >> 4;

  f32x4 acc[2][2];
#pragma unroll
  for (int i = 0; i < 2; ++i)
#pragma unroll
    for (int j = 0; j < 2; ++j) acc[i][j] = {0.f, 0.f, 0.f, 0.f};

  // staging: 4 16B-units per thread per matrix per K-step.
  // LDS linear [row][unit 0..15]; global source unit = lds_unit ^ (row&7).
  const ushort* gA[4];
  const ushort* gB[4];
#pragma unroll
  for (int i = 0; i < 4; ++i) {
    int u = i * 256 + tid;
    int row = u >> 4, c = (u & 15) ^ (row & 7);
    gA[i] = A + (size_t)(m0 + row) * K + c * 8;
    gB[i] = W + (size_t)(n0 + row) * K + c * 8;
  }

  auto stage = [&](int buf, int k0) {
#pragma unroll
    for (int i = 0; i < 4; ++i)
      GLOAD_LDS16(gA[i] + k0, &As[buf][(i * 256 + w * 64) * 8]);
#pragma unroll
    for (int i = 0; i < 4; ++i)
      GLOAD_LDS16(gB[i] + k0, &Bs[buf][(i * 256 + w * 64) * 8]);
  };

  const int nt = K >> 7;
  stage(0, 0);
  for (int t = 0; t < nt; ++t) {
    const int buf = t & 1;
    if (t + 1 < nt) {
      stage(buf ^ 1, (t + 1) << 7);
      asm volatile("s_waitcnt vmcnt(8)" ::: "memory");
    } else {
      asm volatile("s_waitcnt vmcnt(0)" ::: "memory");
    }
    __builtin_amdgcn_s_barrier();
    __builtin_amdgcn_sched_barrier(0);

    short8 a[2][4], b[2][4];
#pragma unroll
    for (int m = 0; m < 2; ++m)
#pragma unroll
      for (int kc = 0; kc < 4; ++kc) {
        int r = wr * 32 + m * 16 + fr;
        a[m][kc] = *reinterpret_cast<const short8*>(
            &As[buf][(r * 16 + ((kc * 4 + g) ^ (r & 7))) * 8]);
      }
#pragma unroll
    for (int n = 0; n < 2; ++n)
#pragma unroll
      for (int kc = 0; kc < 4; ++kc) {
        int r = wc * 32 + n * 16 + fr;
        b[n][kc] = *reinterpret_cast<const short8*>(
            &Bs[buf][(r * 16 + ((kc * 4 + g) ^ (r & 7))) * 8]);
      }
#pragma unroll
    for (int m = 0; m < 2; ++m)
#pragma unroll
      for (int n = 0; n < 2; ++n)
#pragma unroll
        for (int kc = 0; kc < 4; ++kc)
          acc[m][n] = __builtin_amdgcn_mfma_f32_16x16x32_bf16(
              a[m][kc], b[n][kc], acc[m][n], 0, 0, 0);

    __builtin_amdgcn_sched_barrier(0);
    __builtin_amdgcn_s_barrier();
  }

  float bv[2];
#pragma unroll
  for (int n = 0; n < 2; ++n) bv[n] = bias[n0 + wc * 32 + n * 16 + fr];
#pragma unroll
  for (int m = 0; m < 2; ++m) {
#pragma unroll
    for (int j = 0; j < 4; ++j) {
      int row = m0 + wr * 32 + m * 16 + g * 4 + j;
#pragma unroll
      for (int n = 0; n < 2; ++n) {
        int col = n0 + wc * 32 + n * 16 + fr;
        float v = acc[m][n][j] + bv[n];
        if (RELU) v = fmaxf(v, 0.f);
        if constexpr (sizeof(OutT) == 2)
          C[(size_t)row * Nn + col] = (OutT)f2bf(v);
        else
          C[(size_t)row * Nn + col] = (OutT)v;
      }
    }
  }
}

// ---------------------------------------------------------------- banded MFMA attention
// QK: [N,1024] bf16 (q | k), V: [N,512] bf16, Ctx: [N,512] bf16.
// Double-buffered K (global_load_lds) and V (reg->LDS, T14 split):
// next tile's loads issued at tile top, drained after PV — latency hidden.
__global__ __launch_bounds__(256) void attn_mfma(
    const ushort* __restrict__ QK, const ushort* __restrict__ V,
    ushort* __restrict__ Ctx)
{
  constexpr int PAD = 72;
  __shared__ __align__(16) ushort Ks[2][64 * 64];   // XOR-swizzled 16B units
  __shared__ __align__(16) ushort Vt[2][64][PAD];   // transposed V: [d][j]
  __shared__ __align__(16) ushort Pl[4][16][PAD];   // per-wave P
  const int tid = threadIdx.x;
  const int lane = tid & 63, w = tid >> 6;
  const int l15 = lane & 15, g = lane >> 4;
  const int bh = blockIdx.y;
  const int b = bh >> 3, h = bh & 7;
  const int r0 = blockIdx.x * 64;
  const int rowbase = b * kT;
  const int qrow0 = r0 + w * 16;
  const int t_lo = max(r0 - 256, 0);
  const int t_last = min(r0 + 256, kT - 64);
  const int ntiles = ((t_last - t_lo) >> 6) + 1;

  short8 qf[2];
  {
    const size_t qb = (size_t)(rowbase + qrow0 + l15) * 1024 + h * 64 + g * 8;
    qf[0] = *reinterpret_cast<const short8*>(&QK[qb]);
    qf[1] = *reinterpret_cast<const short8*>(&QK[qb + 32]);
  }

  uint4 vreg[2];
  auto issueK = [&](int buf, int j0) {
#pragma unroll
    for (int c = 0; c < 2; ++c) {
      int u = c * 256 + tid;
      int row = u >> 3;
      int col8 = (u & 7) ^ (row & 7);
      const ushort* src =
          &QK[(size_t)(rowbase + j0 + row) * 1024 + 512 + h * 64 + col8 * 8];
      GLOAD_LDS16(src, &Ks[buf][(c * 256 + w * 64) * 8]);
    }
  };
  auto issueV = [&](int j0) {
#pragma unroll
    for (int i = 0; i < 2; ++i)
      vreg[i] = *reinterpret_cast<const uint4*>(
          &V[(size_t)(rowbase + j0 + lane) * 512 + h * 64 + (w + 4 * i) * 8]);
  };
  auto writeV = [&](int buf) {
#pragma unroll
    for (int i = 0; i < 2; ++i) {
      int dg = w + 4 * i;
      ushort tmp[8];
      *reinterpret_cast<uint4*>(tmp) = vreg[i];
#pragma unroll
      for (int e = 0; e < 8; ++e) Vt[buf][dg * 8 + e][lane] = tmp[e];
    }
  };

  f32x4 acc[4];
#pragma unroll
  for (int d = 0; d < 4; ++d) acc[d] = {0.f, 0.f, 0.f, 0.f};
  float mrun[4] = {-1e30f, -1e30f, -1e30f, -1e30f};
  float lrun[4] = {0.f, 0.f, 0.f, 0.f};

  // prologue: tile 0 into buffer 0
  issueK(0, t_lo);
  issueV(t_lo);
  asm volatile("s_waitcnt vmcnt(0)" ::: "memory");
  writeV(0);
  __syncthreads();

  for (int tt = 0; tt < ntiles; ++tt) {
    const int buf = tt & 1;
    const int j0 = t_lo + tt * 64;
    if (tt + 1 < ntiles) {      // prefetch next tile; drained after PV
      issueK(buf ^ 1, j0 + 64);
      issueV(j0 + 64);
    }

    // S = Q @ K^T
    f32x4 s[4];
#pragma unroll
    for (int n = 0; n < 4; ++n) {
      f32x4 z = {0.f, 0.f, 0.f, 0.f};
#pragma unroll
      for (int kc = 0; kc < 2; ++kc) {
        int row = n * 16 + l15;
        int unit = row * 8 + ((kc * 4 + g) ^ (row & 7));
        short8 kb = *reinterpret_cast<const short8*>(&Ks[buf][unit * 8]);
        z = __builtin_amdgcn_mfma_f32_16x16x32_bf16(qf[kc], kb, z, 0, 0, 0);
      }
      s[n] = z;
    }
    // scale + band mask
#pragma unroll
    for (int n = 0; n < 4; ++n)
#pragma unroll
      for (int j = 0; j < 4; ++j) {
        int col = j0 + n * 16 + l15;
        int qr = qrow0 + g * 4 + j;
        int dlt = col - qr;
        float v = s[n][j] * 0.125f;
        s[n][j] = (dlt > 256 || dlt < -256) ? -1e30f : v;
      }
    // online softmax
    float pn[4][4];
    float sold[4];
#pragma unroll
    for (int j = 0; j < 4; ++j) {
      float mx = fmaxf(fmaxf(s[0][j], s[1][j]), fmaxf(s[2][j], s[3][j]));
      mx = fmaxf(mx, __shfl_xor(mx, 1));
      mx = fmaxf(mx, __shfl_xor(mx, 2));
      mx = fmaxf(mx, __shfl_xor(mx, 4));
      mx = fmaxf(mx, __shfl_xor(mx, 8));
      float mnew = fmaxf(mrun[j], mx);
      float sc = __expf(mrun[j] - mnew);
      mrun[j] = mnew;
      sold[j] = sc;
      float rs = 0.f;
#pragma unroll
      for (int n = 0; n < 4; ++n) {
        float p = __expf(s[n][j] - mnew);
        pn[n][j] = p;
        rs += p;
      }
      rs += __shfl_xor(rs, 1);
      rs += __shfl_xor(rs, 2);
      rs += __shfl_xor(rs, 4);
      rs += __shfl_xor(rs, 8);
      lrun[j] = lrun[j] * sc + rs;
    }
#pragma unroll
    for (int d = 0; d < 4; ++d)
#pragma unroll
      for (int j = 0; j < 4; ++j) acc[d][j] *= sold[j];
    // P -> bf16 -> per-wave LDS (C-layout -> A-fragment reshape)
#pragma unroll
    for (int n = 0; n < 4; ++n)
#pragma unroll
      for (int j = 0; j < 4; ++j)
        Pl[w][g * 4 + j][n * 16 + l15] = f2bf(pn[n][j]);
    asm volatile("s_waitcnt lgkmcnt(0)" ::: "memory");
    __builtin_amdgcn_sched_barrier(0);

    short8 pa[2];
    pa[0] = *reinterpret_cast<const short8*>(&Pl[w][l15][g * 8]);
    pa[1] = *reinterpret_cast<const short8*>(&Pl[w][l15][32 + g * 8]);
    // ctx += P @ V
#pragma unroll
    for (int d = 0; d < 4; ++d) {
#pragma unroll
      for (int kc = 0; kc < 2; ++kc) {
        short8 vb = *reinterpret_cast<const short8*>(
            &Vt[buf][d * 16 + l15][kc * 32 + g * 8]);
        acc[d] = __builtin_amdgcn_mfma_f32_16x16x32_bf16(pa[kc], vb, acc[d], 0, 0, 0);
      }
    }

    if (tt + 1 < ntiles) {      // drain prefetch (hidden under compute above)
      asm volatile("s_waitcnt vmcnt(0)" ::: "memory");
      writeV(buf ^ 1);
    }
    __syncthreads();
  }

  float inv[4];
#pragma unroll
  for (int j = 0; j < 4; ++j) inv[j] = 1.f / lrun[j];
#pragma unroll
  for (int d = 0; d < 4; ++d)
#pragma unroll
    for (int j = 0; j < 4; ++j) {
      float v = acc[d][j] * inv[j];
      Ctx[(size_t)(rowbase + qrow0 + g * 4 + j) * 512 + h * 64 + d * 16 + l15] =
          f2bf(v);
    }
}

// ---------------------------------------------------------------- residual + LayerNorm
__global__ __launch_bounds__(256) void ln_kernel(
    const float* __restrict__ A, const float* __restrict__ Bq,
    const float* __restrict__ G, const float* __restrict__ Bt,
    float* __restrict__ Out, ushort* __restrict__ OutB)
{
  const int lane = threadIdx.x & 63;
  const int wv = threadIdx.x >> 6;
  const int row = blockIdx.x * 4 + wv;
  const size_t base = (size_t)row * kD + lane * 8;

  float4 a0 = *reinterpret_cast<const float4*>(&A[base]);
  float4 a1 = *reinterpret_cast<const float4*>(&A[base + 4]);
  float4 b0 = *reinterpret_cast<const float4*>(&Bq[base]);
  float4 b1 = *reinterpret_cast<const float4*>(&Bq[base + 4]);
  float x[8] = {a0.x + b0.x, a0.y + b0.y, a0.z + b0.z, a0.w + b0.w,
                a1.x + b1.x, a1.y + b1.y, a1.z + b1.z, a1.w + b1.w};
  float s = 0.f, ss = 0.f;
#pragma unroll
  for (int i = 0; i < 8; ++i) { s += x[i]; ss += x[i] * x[i]; }
#pragma unroll
  for (int o = 1; o < 64; o <<= 1) {
    s += __shfl_xor(s, o, 64);
    ss += __shfl_xor(ss, o, 64);
  }
  const float mean = s * (1.f / kD);
  const float var = ss * (1.f / kD) - mean * mean;
  const float rs = rsqrtf(var + 1e-5f);

  const int c = lane * 8;
  float4 g0 = *reinterpret_cast<const float4*>(&G[c]);
  float4 g1 = *reinterpret_cast<const float4*>(&G[c + 4]);
  float4 t0 = *reinterpret_cast<const float4*>(&Bt[c]);
  float4 t1 = *reinterpret_cast<const float4*>(&Bt[c + 4]);
  float y[8];
  y[0] = (x[0] - mean) * rs * g0.x + t0.x;
  y[1] = (x[1] - mean) * rs * g0.y + t0.y;
  y[2] = (x[2] - mean) * rs * g0.z + t0.z;
  y[3] = (x[3] - mean) * rs * g0.w + t0.w;
  y[4] = (x[4] - mean) * rs * g1.x + t1.x;
  y[5] = (x[5] - mean) * rs * g1.y + t1.y;
  y[6] = (x[6] - mean) * rs * g1.z + t1.z;
  y[7] = (x[7] - mean) * rs * g1.w + t1.w;
  *reinterpret_cast<float4*>(&Out[base]) = {y[0], y[1], y[2], y[3]};
  *reinterpret_cast<float4*>(&Out[base + 4]) = {y[4], y[5], y[6], y[7]};
  if (OutB) {
    ushort ob[8];
#pragma unroll
    for (int i = 0; i < 8; ++i) ob[i] = f2bf(y[i]);
    *reinterpret_cast<uint4*>(&OutB[base]) = *reinterpret_cast<uint4*>(ob);
  }
}

// ---------------------------------------------------------------- launch
extern "C" void kernel_launch(void* const* d_in, const int* in_sizes, int n_in,
                              void* d_out, int out_size, void* d_ws, size_t ws_size,
                              hipStream_t stream)
{
  const float* x   = (const float*)d_in[0];
  const float* cw  = (const float*)d_in[2];
  const float* cb  = (const float*)d_in[3];
  const float* ipw = (const float*)d_in[4];
  const float* ipb = (const float*)d_in[5];
  const float* opw = (const float*)d_in[6];
  const float* opb = (const float*)d_in[7];
  const float* g1  = (const float*)d_in[8];
  const float* b1n = (const float*)d_in[9];
  const float* w1  = (const float*)d_in[10];
  const float* bb1 = (const float*)d_in[11];
  const float* w2  = (const float*)d_in[12];
  const float* bb2 = (const float*)d_in[13];
  const float* g2  = (const float*)d_in[14];
  const float* b2n = (const float*)d_in[15];
  float* out = (float*)d_out;

  char* p = (char*)d_ws;
  auto take = [&](size_t bytes) {
    char* q = p; p += (bytes + 255) & ~size_t(255); return q;
  };
  ushort* xb    = (ushort*)take((size_t)kN * kD * 2);
  char*  acat_r =          take((size_t)kN * 3 * kD * 2);   // 12MB region
  ushort* acat  = (ushort*)acat_r;
  ushort* wcat  = (ushort*)take((size_t)kD * 3 * kD * 2);
  ushort* ipwb  = (ushort*)take((size_t)3 * kD * kD * 2);
  ushort* opwb  = (ushort*)take((size_t)kD * kD * 2);
  ushort* w1b   = (ushort*)take((size_t)2 * kD * kD * 2);
  ushort* w2b   = (ushort*)take((size_t)2 * kD * kD * 2);
  ushort* convo = (ushort*)take((size_t)kN * kD * 2);
  char*  qk_r   =          take((size_t)kN * 2 * kD * 2);   // 8MB, bf16 q|k
  ushort* qkb   = (ushort*)qk_r;
  ushort* vbb   = (ushort*)take((size_t)kN * kD * 2);
  ushort* ctx   = (ushort*)take((size_t)kN * kD * 2);
  float* hbuf   = (float*)take((size_t)kN * kD * 4);
  ushort* hb    = (ushort*)take((size_t)kN * kD * 2);
  float* attno  = (float*)acat_r;    // acat dead after conv GEMM
  ushort* f1    = (ushort*)qk_r;     // qkb dead after attention
  float* f2     = (float*)acat_r;    // attno dead after LN1

  dim3 blk(256);
  // fused prep: all casts + conv-weight transform + im2col
  prep_kernel<<<dim3(2048), blk, 0, stream>>>(
      x, ipw, opw, w1, w2, cw, xb, ipwb, opwb, w1b, w2b, wcat, acat);

  // conv as GEMM -> bf16
  gemm_bf16<ushort, 0><<<dim3(kN / 64, kD / 64), blk, 0, stream>>>(
      acat, wcat, cb, convo, kN, kD, 3 * kD);
  // q,k projection -> bf16
  gemm_bf16<ushort, 0><<<dim3(kN / 64, 1024 / 64), blk, 0, stream>>>(
      xb, ipwb, ipb, qkb, kN, 1024, kD);
  // v projection -> bf16
  gemm_bf16<ushort, 0><<<dim3(kN / 64, kD / 64), blk, 0, stream>>>(
      convo, ipwb + (size_t)1024 * kD, ipb + 1024, vbb, kN, kD, kD);
  // banded MFMA attention -> bf16 ctx
  attn_mfma<<<dim3(kT / 64, kB * 8), blk, 0, stream>>>(qkb, vbb, ctx);
  // out projection -> fp32
  gemm_bf16<float, 0><<<dim3(kN / 64, kD / 64), blk, 0, stream>>>(
      ctx, opwb, opb, attno, kN, kD, kD);
  // h = LN(x + attn_out)
  ln_kernel<<<dim3(kN / 4), blk, 0, stream>>>(x, attno, g1, b1n, hbuf, hb);
  // ffn1 = relu(h @ w1^T + b1) -> bf16
  gemm_bf16<ushort, 1><<<dim3(kN / 64, 1024 / 64), blk, 0, stream>>>(
      hb, w1b, bb1, f1, kN, 1024, kD);
  // ffn2 -> fp32
  gemm_bf16<float, 0><<<dim3(kN / 64, kD / 64), blk, 0, stream>>>(
      f1, w2b, bb2, f2, kN, kD, 2 * kD);
  // out = LN(h + ffn2)
  ln_kernel<<<dim3(kN / 4), blk, 0, stream>>>(hbuf, f2, g2, b2n, out, nullptr);
}